// Round 13
// baseline (346.939 us; speedup 1.0000x reference)
//
#include <hip/hip_runtime.h>
#include <math.h>

// ---------------------------------------------------------------------------
// ProbMambaHead: time-varying SSM + per-step Kalman filter.
// Phase 0 (prep_kernel): cast W_B + head weights to fp16, PRE-SWIZZLED into
//   MFMA fragment lane order.
// Phase 1 (proj_kernel): MFMA projections, TM=256 tokens/block, 512 thr
//   (8 waves, 1 block/CU): all waves sweep W_i in phase -> W_i fetched to L1
//   once per CU per i. hx written to LDS then flushed coalesced.
// Phase 2 (scan_kernel): sequence-parallel Kalman scan, 32 chunks x 64 owned
//   steps (DS-pipe-throughput-bound: fewer/longer chunks = less total DS
//   work), 10-step warm-up. nll accumulated via device atomics (no finalize).
// ---------------------------------------------------------------------------

#define FENCE() asm volatile("" ::: "memory")   // compiler-only fence; DS ops
// within one wave execute in order, so wave-synchronous LDS needs no barrier.

constexpr int NB   = 32;
constexpr int TSEQ = 2048;
constexpr int BT   = NB * TSEQ;   // 65536
constexpr int DF   = 128;
constexpr int NS   = 16;          // state dim n
constexpr int DYV  = 8;           // obs dim dy
constexpr int REC  = 192;         // floats per (b,t) record (48 float4)
constexpr int TM   = 256;         // tokens per proj block
constexpr int SST  = 17;          // sigS/bbS row stride (pad 16 -> 17)

constexpr int CL   = 64;          // owned steps per scan chunk
constexpr int WU   = 10;          // warmup steps
constexpr int NC   = TSEQ / CL;   // 32 chunks per batch

#define LOG2PI_F 1.8378770664093453f

typedef __attribute__((ext_vector_type(8))) _Float16 f16x8;
typedef __attribute__((ext_vector_type(4))) _Float16 f16x4;
typedef __attribute__((ext_vector_type(4))) float    f32x4;

__device__ __forceinline__ float sp_(float v) {          // jax.nn.softplus
    return v > 0.f ? v + log1pf(expf(-v)) : log1pf(expf(v));
}
__device__ __forceinline__ float dot4_(float4 a, float4 b) {
    return a.x*b.x + a.y*b.y + a.z*b.z + a.w*b.w;
}
__device__ __forceinline__ float dot16a(const float cz[16], const float* p) {
    const float4* p4 = (const float4*)p;
    float4 x0 = p4[0], x1 = p4[1], x2 = p4[2], x3 = p4[3];
    return cz[0]*x0.x + cz[1]*x0.y + cz[2]*x0.z + cz[3]*x0.w
         + cz[4]*x1.x + cz[5]*x1.y + cz[6]*x1.z + cz[7]*x1.w
         + cz[8]*x2.x + cz[9]*x2.y + cz[10]*x2.z + cz[11]*x2.w
         + cz[12]*x3.x + cz[13]*x3.y + cz[14]*x3.z + cz[15]*x3.w;
}
// uniform broadcast from a compile-time lane: scalar pipe, not DS
__device__ __forceinline__ float rdlane(float v, int lane) {
    return __int_as_float(__builtin_amdgcn_readlane(__float_as_int(v), lane));
}

// ---------------------------------------------------------------------------
// Phase 0: weight cast to fp16, swizzled into MFMA fragment lane order.
// WBh (A-fragment order): flat = i*16384 + p*512 + l*8 + j, p = ft*4+ch;
//   source = M_i[ft*16 + (l&15)][ch*32 + (l>>4)*8 + j].
// WHh (B-fragment order): flat = ((nt*4+ch)*64 + l)*8 + j;
//   head h = nt*16 + (l&15); k = ch*32 + (l>>4)*8 + j.
//   h<128: C row h | 128..143: sig | 144..151: R | 152: gate | 153..168: bB
//   | 169..175: zero.
// ---------------------------------------------------------------------------
__global__ __launch_bounds__(256) void prep_kernel(
    const float* __restrict__ WBm, const float* __restrict__ Wg,
    const float* __restrict__ Wsg, const float* __restrict__ WR,
    const float* __restrict__ WC,  const float* __restrict__ bB,
    _Float16* __restrict__ WBh, _Float16* __restrict__ WHh)
{
    int idx = blockIdx.x * 256 + threadIdx.x;
    if (idx < 2048 * 128) {
        int j = idx & 7, l = (idx >> 3) & 63, p = (idx >> 9) & 31, i = idx >> 14;
        int row = (p >> 2) * 16 + (l & 15);
        int col = (p & 3) * 32 + (l >> 4) * 8 + j;
        WBh[idx] = (_Float16)WBm[((size_t)i * 128 + row) * 128 + col];
        return;
    }
    idx -= 2048 * 128;
    if (idx >= 11 * 2048) return;            // 11 tiles * 4 * 64 * 8 = 22528
    int j = idx & 7, l = (idx >> 3) & 63, ch = (idx >> 9) & 3, nt = idx >> 11;
    int h = nt * 16 + (l & 15);
    int g = ch * 32 + (l >> 4) * 8 + j;
    float v;
    if (h < 128)       v = WC[h * 128 + g];
    else if (h < 144)  v = Wsg[(h - 128) * 128 + g];
    else if (h < 152)  v = WR[(h - 144) * 128 + g];
    else if (h == 152) v = Wg[g];
    else if (h < 169)  v = bB[(h - 153) * 128 + g];
    else               v = 0.f;
    WHh[idx] = (_Float16)v;
}

// ---------------------------------------------------------------------------
// Phase 1: MFMA projections. Block = 512 thr (8 waves), 256 tokens.
// Record layout: [0:16) exp_z | [16:32) hx | [32:48) q | [48:176) C (d*16+j)
//                | [176:184) R | [184:192) y.
// ---------------------------------------------------------------------------
__global__ __launch_bounds__(512) void proj_kernel(
    const float* __restrict__ x, const float* __restrict__ y,
    const float* __restrict__ a_raw,
    const float* __restrict__ bg, const float* __restrict__ bsg,
    const float* __restrict__ bR, const float* __restrict__ bC,
    const _Float16* __restrict__ WBh, const _Float16* __restrict__ WHh,
    float* __restrict__ rec)
{
    __shared__ __align__(16) _Float16 Xs[TM * 136];   // [tok][f] fp16, pad 136
    __shared__ __align__(16) float Dsh[TM];           // Delta
    __shared__ __align__(16) float sigS[TM * SST];    // sigma -> gamma*Delta
    __shared__ __align__(16) float bbS[TM * SST];     // bB.x -> (stage Q) hx

    const int tid = threadIdx.x;
    const long bt0 = (long)blockIdx.x * TM;
    const int l  = tid & 63, w = tid >> 6;            // w in [0,8)
    const int lm = l & 15,  lg = l >> 4;

    // ---- stage X: load fp32 tile -> fp16 LDS; y -> rec
    {
        const float4* x4 = (const float4*)(x + bt0 * DF);
        #pragma unroll
        for (int k = 0; k < 16; ++k) {
            int idx = tid + k * 512;           // 8192 float4 = 256x128
            int tok = idx >> 5, fg = idx & 31;
            float4 v = x4[idx];
            f16x4 hv = { (_Float16)v.x, (_Float16)v.y, (_Float16)v.z, (_Float16)v.w };
            *(f16x4*)(Xs + tok * 136 + fg * 4) = hv;
        }
        float4 yv = ((const float4*)(y + bt0 * DYV))[tid];   // 512 float4
        *(float4*)(rec + (bt0 + (tid >> 1)) * REC + 184 + (tid & 1) * 4) = yv;
    }
    __syncthreads();

    // ---- stage H: head GEMM, wave w owns token-tiles {2w, 2w+1}.
    for (int nt = 0; nt < 11; ++nt) {
        f16x8 wf[4];
        #pragma unroll
        for (int ch = 0; ch < 4; ++ch)
            wf[ch] = *(const f16x8*)(WHh + ((nt * 4 + ch) * 64 + l) * 8);
        #pragma unroll
        for (int tt2 = 0; tt2 < 2; ++tt2) {
            const int tt = 2 * w + tt2;
            f32x4 acc = {0.f, 0.f, 0.f, 0.f};
            #pragma unroll
            for (int ch = 0; ch < 4; ++ch) {
                f16x8 xf = *(const f16x8*)(Xs + (tt * 16 + lm) * 136 + ch * 32 + lg * 8);
                acc = __builtin_amdgcn_mfma_f32_16x16x32_f16(xf, wf[ch], acc, 0, 0, 0);
            }
            const int tokb = tt * 16 + lg * 4;           // + reg
            if (nt < 8) {                                // pure C tiles
                float bias = bC[nt * 16 + lm];
                #pragma unroll
                for (int rg = 0; rg < 4; ++rg)
                    rec[(bt0 + tokb + rg) * REC + 48 + nt * 16 + lm] = acc[rg] + bias;
            } else if (nt == 8) {                        // pure sig tile
                float bias = bsg[lm];
                #pragma unroll
                for (int rg = 0; rg < 4; ++rg)
                    sigS[(tokb + rg) * SST + lm] = sp_(acc[rg] + bias) + 1e-6f + 1e-3f;
            } else if (nt == 9) {                        // R | gate | bB 0..6
                #pragma unroll
                for (int rg = 0; rg < 4; ++rg) {
                    int tok = tokb + rg; float v = acc[rg];
                    if (lm < 8)
                        rec[(bt0 + tok) * REC + 176 + lm] = sp_(v + bR[lm]) + 1e-6f + 1e-4f;
                    else if (lm == 8)
                        Dsh[tok] = fminf(fmaxf(sp_(v + bg[0]) + 1e-6f, 1e-3f), 1.0f);
                    else
                        bbS[tok * SST + (lm - 9)] = v;
                }
            } else {                                     // bB 7..15 | pad
                #pragma unroll
                for (int rg = 0; rg < 4; ++rg)
                    if (lm < 9) bbS[(tokb + rg) * SST + 7 + lm] = acc[rg];
            }
        }
    }
    __syncthreads();

    // ---- stage Z: per (t,i) ez/q; sigS becomes gamma*Delta in place
    for (int p = tid; p < TM * NS; p += 512) {
        int t = p >> 4, i = p & 15;
        float D  = Dsh[t];
        float a  = -(sp_(a_raw[i]) + 1e-6f);
        float z  = fminf(fmaxf(D * a, -20.f), 20.f);
        float ez = expf(z);
        float gam = (fabsf(z) < 1e-4f) ? (1.f + 0.5f * z) : (expm1f(z) / z);
        float z2  = 2.f * z;
        float rho = (fabsf(z2) < 1e-4f) ? (1.f + 0.5f * z2) : (expm1f(z2) / z2);
        float sg  = sigS[t * SST + i];
        long base = (bt0 + t) * REC;
        rec[base + i]      = ez;
        rec[base + 32 + i] = sg * sg * rho * D;
        sigS[t * SST + i] = gam * D;             // now gamma*Delta
    }
    __syncthreads();                             // sigS/bbS ready for epilogue

    // ---- hoist B-fragments (loop-invariant over i): wave w's tokens
    f16x8 b0[4], b1[4];
    #pragma unroll
    for (int ch = 0; ch < 4; ++ch) {
        b0[ch] = *(const f16x8*)(Xs + ((2 * w) * 16 + lm) * 136 + ch * 32 + lg * 8);
        b1[ch] = *(const f16x8*)(Xs + ((2 * w + 1) * 16 + lm) * 136 + ch * 32 + lg * 8);
    }

    // ---- stage Q: quadratic form. All 8 waves sweep i in phase: W_i (32KB)
    // is fetched into L1 once per CU per i. hx -> bbS in place (LDS).
    for (int i = 0; i < 16; ++i) {
        const _Float16* Wi = WBh + (size_t)i * 16384;
        f32x4 acc[2][8];
        #pragma unroll
        for (int tt = 0; tt < 2; ++tt)
            #pragma unroll
            for (int ft = 0; ft < 8; ++ft) acc[tt][ft] = (f32x4){0.f, 0.f, 0.f, 0.f};
        #pragma unroll
        for (int ch = 0; ch < 4; ++ch) {
            f16x8 af[8];
            #pragma unroll
            for (int ft = 0; ft < 8; ++ft)
                af[ft] = *(const f16x8*)(Wi + (ft * 4 + ch) * 512 + l * 8);
            #pragma unroll
            for (int ft = 0; ft < 8; ++ft) {
                acc[0][ft] = __builtin_amdgcn_mfma_f32_16x16x32_f16(af[ft], b0[ch], acc[0][ft], 0, 0, 0);
                acc[1][ft] = __builtin_amdgcn_mfma_f32_16x16x32_f16(af[ft], b1[ch], acc[1][ft], 0, 0, 0);
            }
        }
        // in-register contraction over f, then 2 shfl hops over lane groups
        #pragma unroll
        for (int tt = 0; tt < 2; ++tt) {
            int tok16 = (2 * w + tt) * 16;
            float part = 0.f;
            #pragma unroll
            for (int ft = 0; ft < 8; ++ft) {
                f16x4 xv = *(const f16x4*)(Xs + (tok16 + lm) * 136 + ft * 16 + lg * 4);
                part += acc[tt][ft][0] * (float)xv[0] + acc[tt][ft][1] * (float)xv[1]
                      + acc[tt][ft][2] * (float)xv[2] + acc[tt][ft][3] * (float)xv[3];
            }
            part += __shfl_xor(part, 16, 64);
            part += __shfl_xor(part, 32, 64);
            if (l < 16) {
                int t = tok16 + l;
                bbS[t * SST + i] = sigS[t * SST + i] * (part + bbS[t * SST + i]);
            }
        }
    }
    __syncthreads();

    // ---- flush hx (bbS) coalesced: 16 consecutive floats per token
    for (int idx = tid; idx < TM * 4; idx += 512) {
        int t = idx >> 2, g = (idx & 3) * 4;
        const float* hp = bbS + t * SST + g;
        *(float4*)(rec + (bt0 + t) * REC + 16 + g) =
            make_float4(hp[0], hp[1], hp[2], hp[3]);
    }
}

// ---------------------------------------------------------------------------
// Phase 2: sequence-parallel Kalman scan. Block = (b, chunk c). Chunk owns
// t in [c*CL, (c+1)*CL); warm-started WU steps early from generic init.
// Log-likelihood reduced via device-scope float atomics into out_sc[0..1]
// (zeroed by hipMemsetAsync before launch).
// ---------------------------------------------------------------------------
__global__ __launch_bounds__(64) void scan_kernel(
    const float* __restrict__ rec, const float* __restrict__ p0,
    float* __restrict__ out_ym, float* __restrict__ out_var,
    float* __restrict__ out_sc)
{
    const int blk = blockIdx.x;
    const int b   = blk / NC;
    const int c   = blk - b * NC;
    const int t0  = c * CL;                 // first owned step
    const int ts  = (c == 0) ? 0 : (t0 - WU);
    const int nst = t0 + CL - ts;           // total steps this block runs

    const int l  = threadIdx.x;
    const int d8 = l >> 3, c8 = l & 7;        // (row d, col-group) for CP/S/GJ
    const int i4 = l >> 2, j4 = (l & 3) * 4;  // (row i, col-block) for P stage

    __shared__ __align__(16) float Ps[2][REC];     // double-buffered record
    __shared__ __align__(16) float Pm[16 * 20];    // P, row stride 20 (padded)
    __shared__ __align__(16) float CPm[8 * 20];    // CP rows [d][m], stride 20
    __shared__ __align__(16) float CPT[16 * 12];   // CP^T rows [m][d], stride 12
    __shared__ __align__(16) float XT[16 * 12];    // X^T rows  [m][d], stride 12
    __shared__ __align__(16) float hS[NS];
    __shared__ __align__(16) float v8[DYV];

    // init: h = 0, P = diag(|p0|)  (exact for c==0; warmup-forgotten otherwise)
    {
        float pv = fabsf(p0[i4]);
        float4 t4;
        t4.x = (j4 + 0 == i4) ? pv : 0.f;  t4.y = (j4 + 1 == i4) ? pv : 0.f;
        t4.z = (j4 + 2 == i4) ? pv : 0.f;  t4.w = (j4 + 3 == i4) ? pv : 0.f;
        *(float4*)(Pm + i4 * 20 + j4) = t4;
        if (l < NS) hS[l] = 0.f;
    }
    const float4* rec4 = (const float4*)(rec + ((size_t)b * TSEQ + ts) * REC);
    float4 pf;
    if (l < 48) {
        ((float4*)Ps[0])[l] = rec4[l];     // record for first step
        pf = rec4[48 + l];                 // next record in flight
    }
    FENCE();

    float accll = 0.f;
    for (int k = 0; k < nst; ++k) {
        const int  t   = ts + k;
        const bool own = (t >= t0);
        const float* R_ = Ps[k & 1];
        float*       W_ = Ps[(k & 1) ^ 1];
        const int m0 = 2 * c8, m1 = m0 + 1;

        // ---- CP stage + folded y_pred.
        // cz[j] = C[d8][j]*ez[j]; yp = cz.h + C[d8].hx (all lanes, redundant)
        float cz[16];
        float4 c0, c1, c2, c3;
        {
            const float4* C4 = (const float4*)(R_ + 48 + 16 * d8);
            const float4* E4 = (const float4*)R_;
            c0 = C4[0]; c1 = C4[1]; c2 = C4[2]; c3 = C4[3];
            float4 e0 = E4[0], e1 = E4[1], e2 = E4[2], e3 = E4[3];
            cz[0]=c0.x*e0.x; cz[1]=c0.y*e0.y; cz[2]=c0.z*e0.z; cz[3]=c0.w*e0.w;
            cz[4]=c1.x*e1.x; cz[5]=c1.y*e1.y; cz[6]=c1.z*e1.z; cz[7]=c1.w*e1.w;
            cz[8]=c2.x*e2.x; cz[9]=c2.y*e2.y; cz[10]=c2.z*e2.z; cz[11]=c2.w*e2.w;
            cz[12]=c3.x*e3.x; cz[13]=c3.y*e3.y; cz[14]=c3.z*e3.z; cz[15]=c3.w*e3.w;
        }
        float e_save = 0.f;
        {
            const float4* H4 = (const float4*)hS;
            const float4* X4 = (const float4*)(R_ + 16);
            float4 h0=H4[0], h1=H4[1], h2=H4[2], h3=H4[3];
            float4 x0=X4[0], x1=X4[1], x2=X4[2], x3=X4[3];
            float yp = cz[0]*h0.x + cz[1]*h0.y + cz[2]*h0.z + cz[3]*h0.w
                     + cz[4]*h1.x + cz[5]*h1.y + cz[6]*h1.z + cz[7]*h1.w
                     + cz[8]*h2.x + cz[9]*h2.y + cz[10]*h2.z + cz[11]*h2.w
                     + cz[12]*h3.x + cz[13]*h3.y + cz[14]*h3.z + cz[15]*h3.w
                     + dot4_(c0, x0) + dot4_(c1, x1) + dot4_(c2, x2) + dot4_(c3, x3);
            if (c8 == 0) {
                e_save = R_[184 + d8] - yp;
                if (own) out_ym[((size_t)b * TSEQ + t) * 8 + d8] = yp;
            }
        }
        {
            float ezm0 = R_[m0],        ezm1 = R_[m1];
            float qm0  = R_[32 + m0],   qm1  = R_[32 + m1];
            float Cd0  = R_[48 + 16 * d8 + m0], Cd1 = R_[48 + 16 * d8 + m1];
            float cp0 = ezm0 * dot16a(cz, Pm + m0 * 20) + Cd0 * qm0;
            float cp1 = ezm1 * dot16a(cz, Pm + m1 * 20) + Cd1 * qm1;
            CPm[d8 * 20 + m0] = cp0;  CPm[d8 * 20 + m1] = cp1;
            CPT[m0 * 12 + d8] = cp0;  CPT[m1 * 12 + d8] = cp1;
        }
        float hpred_l = (l < NS) ? (R_[l] * hS[l] + R_[16 + l]) : 0.f;
        FENCE();

        // ---- S stage: augmented row [S(8) | CP(16) | e] distributed 4/lane
        float a0, a1, a2, a3;
        {
            const float4* CPr = (const float4*)(CPm + d8 * 20);
            const float4* Ce  = (const float4*)(R_ + 48 + 16 * c8);
            a0 = dot4_(CPr[0], Ce[0]) + dot4_(CPr[1], Ce[1])
               + dot4_(CPr[2], Ce[2]) + dot4_(CPr[3], Ce[3]);
            a1 = CPm[d8 * 20 + c8];
            a2 = CPm[d8 * 20 + c8 + 8];
            a3 = e_save;
            if (d8 == c8) {
                a0 += R_[176 + d8];
                if (own) out_var[((size_t)b * TSEQ + t) * 8 + d8] = a0;
            }
        }
        // stage next record + prefetch (independent of the chain)
        if (l < 48) {
            ((float4*)W_)[l] = pf;
            if (k + 2 < nst) pf = rec4[(size_t)(k + 2) * 48 + l];
        }
        FENCE();

        // ---- Gauss-Jordan on [S | CP | e]: ends as [I | X | v], det = prod piv
        // piv and b3 are uniform broadcasts from compile-time lanes -> readlane
        float pdet = 1.f;
        #pragma unroll
        for (int kk = 0; kk < 8; ++kk) {
            float piv = rdlane(a0, kk * 9);
            float b3  = rdlane(a3, kk * 8);
            float f_  = __shfl(a0, (d8 << 3) | kk, 64);
            float b0  = __shfl(a0, (kk << 3) | c8, 64);
            float b1  = __shfl(a1, (kk << 3) | c8, 64);
            float b2  = __shfl(a2, (kk << 3) | c8, 64);
            pdet *= piv;
            float ip = __builtin_amdgcn_rcpf(piv);
            ip = ip * (2.f - piv * ip);            // Newton: full fp32 rcp
            float fr = f_ * ip;
            if (d8 == kk) { a0 *= ip; a1 *= ip; a2 *= ip; a3 *= ip; }
            else          { a0 -= fr * b0; a1 -= fr * b1; a2 -= fr * b2; a3 -= fr * b3; }
        }

        // ---- publish X^T, v
        XT[c8 * 12 + d8]       = a1;
        XT[(c8 + 8) * 12 + d8] = a2;
        if (c8 == 0) v8[d8] = a3;
        FENCE();

        // log-likelihood (lanes c8==0 hold v[d8]; reduce over d8)
        {
            float qp = e_save * a3;
            qp += __shfl_xor(qp, 8, 64);
            qp += __shfl_xor(qp, 16, 64);
            qp += __shfl_xor(qp, 32, 64);
            if (l == 0 && own) accll += -0.5f * (logf(pdet) + qp + 8.f * LOG2PI_F);
        }
        // h_new (lanes 0..15): h = hpred + CP^T v
        if (l < NS) {
            const float4* ct = (const float4*)(CPT + l * 12);
            const float4* vv = (const float4*)v8;
            hS[l] = hpred_l + dot4_(ct[0], vv[0]) + dot4_(ct[1], vv[1]);
        }

        // ---- P_new = Ppred - CP^T X (symmetric in exact arithmetic)
        {
            const float4* ct = (const float4*)(CPT + i4 * 12);
            float4 ca = ct[0], cb = ct[1];
            float  ezi = R_[i4];
            float4 ezj = *(const float4*)(R_ + j4);
            float  qi  = R_[32 + i4];
            float4 po  = *(const float4*)(Pm + i4 * 20 + j4);
            float pol[4]  = {po.x, po.y, po.z, po.w};
            float ezjl[4] = {ezj.x, ezj.y, ezj.z, ezj.w};
            float pn[4];
            #pragma unroll
            for (int m = 0; m < 4; ++m) {
                int j = j4 + m;
                const float4* xt = (const float4*)(XT + j * 12);
                float dt = dot4_(ca, xt[0]) + dot4_(cb, xt[1]);
                float pp = ezi * ezjl[m] * pol[m] + ((j == i4) ? qi : 0.f);
                pn[m] = pp - dt;
            }
            *(float4*)(Pm + i4 * 20 + j4) = make_float4(pn[0], pn[1], pn[2], pn[3]);
        }
        FENCE();
    }
    if (l == 0) {
        atomicAdd(&out_sc[0], -accll / (float)NB);   // nll
        atomicAdd(&out_sc[1],  accll / (float)BT);   // avg_ll_per_step
    }
}

extern "C" void kernel_launch(void* const* d_in, const int* in_sizes, int n_in,
                              void* d_out, int out_size, void* d_ws, size_t ws_size,
                              hipStream_t stream) {
    const float* x     = (const float*)d_in[0];
    const float* y     = (const float*)d_in[1];
    const float* a_raw = (const float*)d_in[2];
    const float* Wg    = (const float*)d_in[3];
    const float* bg    = (const float*)d_in[4];
    const float* WBm   = (const float*)d_in[5];
    const float* bB    = (const float*)d_in[6];
    const float* WC    = (const float*)d_in[7];
    const float* bC    = (const float*)d_in[8];
    const float* Wsg   = (const float*)d_in[9];
    const float* bsg   = (const float*)d_in[10];
    const float* WR    = (const float*)d_in[11];
    const float* bR    = (const float*)d_in[12];
    const float* p0    = (const float*)d_in[13];

    float* rec   = (float*)d_ws;                        // 65536*192*4 = 50.3 MB
    _Float16* WBh = (_Float16*)(rec + (size_t)BT * REC); // 2048*128 fp16 swizzled
    _Float16* WHh = WBh + 2048 * 128;                   // 176*128 fp16 swizzled
    float* out   = (float*)d_out;
    float* out_sc = out + (size_t)2 * BT * DYV;         // [nll, avg_ll]

    hipMemsetAsync(out_sc, 0, 2 * sizeof(float), stream);
    prep_kernel<<<(2048 * 128 + 11 * 2048 + 255) / 256, 256, 0, stream>>>(
        WBm, Wg, Wsg, WR, WC, bB, WBh, WHh);
    proj_kernel<<<BT / TM, 512, 0, stream>>>(x, y, a_raw, bg, bsg, bR, bC,
                                             WBh, WHh, rec);
    scan_kernel<<<NB * NC, 64, 0, stream>>>(rec, p0, out, out + (size_t)BT * DYV,
                                            out_sc);
}

// Round 14
// 319.977 us; speedup vs baseline: 1.0843x; 1.0843x over previous
//
#include <hip/hip_runtime.h>
#include <math.h>

// ---------------------------------------------------------------------------
// ProbMambaHead: time-varying SSM + per-step Kalman filter.
// Phase 0 (prep_kernel): cast W_B + head weights to fp16, PRE-SWIZZLED into
//   MFMA fragment lane order.
// Phase 1 (proj_kernel): MFMA projections, TM=256 tokens/block, 512 thr
//   (8 waves, 1 block/CU): all waves sweep W_i in phase -> W_i fetched to L1
//   once per CU per i. hx written to LDS then flushed coalesced.
// Phase 2 (scan_kernel): sequence-parallel Kalman scan, 64 chunks x 32 owned
//   steps, 10-step warm-up. CL=32 is the measured latency/DS-throughput
//   balance point (R13: CL=64 regressed 109->169us). nll via device atomics.
// ---------------------------------------------------------------------------

#define FENCE() asm volatile("" ::: "memory")   // compiler-only fence; DS ops
// within one wave execute in order, so wave-synchronous LDS needs no barrier.

constexpr int NB   = 32;
constexpr int TSEQ = 2048;
constexpr int BT   = NB * TSEQ;   // 65536
constexpr int DF   = 128;
constexpr int NS   = 16;          // state dim n
constexpr int DYV  = 8;           // obs dim dy
constexpr int REC  = 192;         // floats per (b,t) record (48 float4)
constexpr int TM   = 256;         // tokens per proj block
constexpr int SST  = 17;          // sigS/bbS row stride (pad 16 -> 17)

constexpr int CL   = 32;          // owned steps per scan chunk (measured opt)
constexpr int WU   = 10;          // warmup steps
constexpr int NC   = TSEQ / CL;   // 64 chunks per batch

#define LOG2PI_F 1.8378770664093453f

typedef __attribute__((ext_vector_type(8))) _Float16 f16x8;
typedef __attribute__((ext_vector_type(4))) _Float16 f16x4;
typedef __attribute__((ext_vector_type(4))) float    f32x4;

__device__ __forceinline__ float sp_(float v) {          // jax.nn.softplus
    return v > 0.f ? v + log1pf(expf(-v)) : log1pf(expf(v));
}
__device__ __forceinline__ float dot4_(float4 a, float4 b) {
    return a.x*b.x + a.y*b.y + a.z*b.z + a.w*b.w;
}
__device__ __forceinline__ float dot16a(const float cz[16], const float* p) {
    const float4* p4 = (const float4*)p;
    float4 x0 = p4[0], x1 = p4[1], x2 = p4[2], x3 = p4[3];
    return cz[0]*x0.x + cz[1]*x0.y + cz[2]*x0.z + cz[3]*x0.w
         + cz[4]*x1.x + cz[5]*x1.y + cz[6]*x1.z + cz[7]*x1.w
         + cz[8]*x2.x + cz[9]*x2.y + cz[10]*x2.z + cz[11]*x2.w
         + cz[12]*x3.x + cz[13]*x3.y + cz[14]*x3.z + cz[15]*x3.w;
}
// uniform broadcast from a compile-time lane: scalar pipe, not DS
__device__ __forceinline__ float rdlane(float v, int lane) {
    return __int_as_float(__builtin_amdgcn_readlane(__float_as_int(v), lane));
}

// ---------------------------------------------------------------------------
// Phase 0: weight cast to fp16, swizzled into MFMA fragment lane order.
// WBh (A-fragment order): flat = i*16384 + p*512 + l*8 + j, p = ft*4+ch;
//   source = M_i[ft*16 + (l&15)][ch*32 + (l>>4)*8 + j].
// WHh (B-fragment order): flat = ((nt*4+ch)*64 + l)*8 + j;
//   head h = nt*16 + (l&15); k = ch*32 + (l>>4)*8 + j.
//   h<128: C row h | 128..143: sig | 144..151: R | 152: gate | 153..168: bB
//   | 169..175: zero.
// ---------------------------------------------------------------------------
__global__ __launch_bounds__(256) void prep_kernel(
    const float* __restrict__ WBm, const float* __restrict__ Wg,
    const float* __restrict__ Wsg, const float* __restrict__ WR,
    const float* __restrict__ WC,  const float* __restrict__ bB,
    _Float16* __restrict__ WBh, _Float16* __restrict__ WHh)
{
    int idx = blockIdx.x * 256 + threadIdx.x;
    if (idx < 2048 * 128) {
        int j = idx & 7, l = (idx >> 3) & 63, p = (idx >> 9) & 31, i = idx >> 14;
        int row = (p >> 2) * 16 + (l & 15);
        int col = (p & 3) * 32 + (l >> 4) * 8 + j;
        WBh[idx] = (_Float16)WBm[((size_t)i * 128 + row) * 128 + col];
        return;
    }
    idx -= 2048 * 128;
    if (idx >= 11 * 2048) return;            // 11 tiles * 4 * 64 * 8 = 22528
    int j = idx & 7, l = (idx >> 3) & 63, ch = (idx >> 9) & 3, nt = idx >> 11;
    int h = nt * 16 + (l & 15);
    int g = ch * 32 + (l >> 4) * 8 + j;
    float v;
    if (h < 128)       v = WC[h * 128 + g];
    else if (h < 144)  v = Wsg[(h - 128) * 128 + g];
    else if (h < 152)  v = WR[(h - 144) * 128 + g];
    else if (h == 152) v = Wg[g];
    else if (h < 169)  v = bB[(h - 153) * 128 + g];
    else               v = 0.f;
    WHh[idx] = (_Float16)v;
}

// ---------------------------------------------------------------------------
// Phase 1: MFMA projections. Block = 512 thr (8 waves), 256 tokens.
// Record layout: [0:16) exp_z | [16:32) hx | [32:48) q | [48:176) C (d*16+j)
//                | [176:184) R | [184:192) y.
// ---------------------------------------------------------------------------
__global__ __launch_bounds__(512) void proj_kernel(
    const float* __restrict__ x, const float* __restrict__ y,
    const float* __restrict__ a_raw,
    const float* __restrict__ bg, const float* __restrict__ bsg,
    const float* __restrict__ bR, const float* __restrict__ bC,
    const _Float16* __restrict__ WBh, const _Float16* __restrict__ WHh,
    float* __restrict__ rec)
{
    __shared__ __align__(16) _Float16 Xs[TM * 136];   // [tok][f] fp16, pad 136
    __shared__ __align__(16) float Dsh[TM];           // Delta
    __shared__ __align__(16) float sigS[TM * SST];    // sigma -> gamma*Delta
    __shared__ __align__(16) float bbS[TM * SST];     // bB.x -> (stage Q) hx

    const int tid = threadIdx.x;
    const long bt0 = (long)blockIdx.x * TM;
    const int l  = tid & 63, w = tid >> 6;            // w in [0,8)
    const int lm = l & 15,  lg = l >> 4;

    // ---- stage X: load fp32 tile -> fp16 LDS; y -> rec
    {
        const float4* x4 = (const float4*)(x + bt0 * DF);
        #pragma unroll
        for (int k = 0; k < 16; ++k) {
            int idx = tid + k * 512;           // 8192 float4 = 256x128
            int tok = idx >> 5, fg = idx & 31;
            float4 v = x4[idx];
            f16x4 hv = { (_Float16)v.x, (_Float16)v.y, (_Float16)v.z, (_Float16)v.w };
            *(f16x4*)(Xs + tok * 136 + fg * 4) = hv;
        }
        float4 yv = ((const float4*)(y + bt0 * DYV))[tid];   // 512 float4
        *(float4*)(rec + (bt0 + (tid >> 1)) * REC + 184 + (tid & 1) * 4) = yv;
    }
    __syncthreads();

    // ---- stage H: head GEMM, wave w owns token-tiles {2w, 2w+1}.
    for (int nt = 0; nt < 11; ++nt) {
        f16x8 wf[4];
        #pragma unroll
        for (int ch = 0; ch < 4; ++ch)
            wf[ch] = *(const f16x8*)(WHh + ((nt * 4 + ch) * 64 + l) * 8);
        #pragma unroll
        for (int tt2 = 0; tt2 < 2; ++tt2) {
            const int tt = 2 * w + tt2;
            f32x4 acc = {0.f, 0.f, 0.f, 0.f};
            #pragma unroll
            for (int ch = 0; ch < 4; ++ch) {
                f16x8 xf = *(const f16x8*)(Xs + (tt * 16 + lm) * 136 + ch * 32 + lg * 8);
                acc = __builtin_amdgcn_mfma_f32_16x16x32_f16(xf, wf[ch], acc, 0, 0, 0);
            }
            const int tokb = tt * 16 + lg * 4;           // + reg
            if (nt < 8) {                                // pure C tiles
                float bias = bC[nt * 16 + lm];
                #pragma unroll
                for (int rg = 0; rg < 4; ++rg)
                    rec[(bt0 + tokb + rg) * REC + 48 + nt * 16 + lm] = acc[rg] + bias;
            } else if (nt == 8) {                        // pure sig tile
                float bias = bsg[lm];
                #pragma unroll
                for (int rg = 0; rg < 4; ++rg)
                    sigS[(tokb + rg) * SST + lm] = sp_(acc[rg] + bias) + 1e-6f + 1e-3f;
            } else if (nt == 9) {                        // R | gate | bB 0..6
                #pragma unroll
                for (int rg = 0; rg < 4; ++rg) {
                    int tok = tokb + rg; float v = acc[rg];
                    if (lm < 8)
                        rec[(bt0 + tok) * REC + 176 + lm] = sp_(v + bR[lm]) + 1e-6f + 1e-4f;
                    else if (lm == 8)
                        Dsh[tok] = fminf(fmaxf(sp_(v + bg[0]) + 1e-6f, 1e-3f), 1.0f);
                    else
                        bbS[tok * SST + (lm - 9)] = v;
                }
            } else {                                     // bB 7..15 | pad
                #pragma unroll
                for (int rg = 0; rg < 4; ++rg)
                    if (lm < 9) bbS[(tokb + rg) * SST + 7 + lm] = acc[rg];
            }
        }
    }
    __syncthreads();

    // ---- stage Z: per (t,i) ez/q; sigS becomes gamma*Delta in place
    for (int p = tid; p < TM * NS; p += 512) {
        int t = p >> 4, i = p & 15;
        float D  = Dsh[t];
        float a  = -(sp_(a_raw[i]) + 1e-6f);
        float z  = fminf(fmaxf(D * a, -20.f), 20.f);
        float ez = expf(z);
        float gam = (fabsf(z) < 1e-4f) ? (1.f + 0.5f * z) : (expm1f(z) / z);
        float z2  = 2.f * z;
        float rho = (fabsf(z2) < 1e-4f) ? (1.f + 0.5f * z2) : (expm1f(z2) / z2);
        float sg  = sigS[t * SST + i];
        long base = (bt0 + t) * REC;
        rec[base + i]      = ez;
        rec[base + 32 + i] = sg * sg * rho * D;
        sigS[t * SST + i] = gam * D;             // now gamma*Delta
    }
    __syncthreads();                             // sigS/bbS ready for epilogue

    // ---- hoist B-fragments (loop-invariant over i): wave w's tokens
    f16x8 b0[4], b1[4];
    #pragma unroll
    for (int ch = 0; ch < 4; ++ch) {
        b0[ch] = *(const f16x8*)(Xs + ((2 * w) * 16 + lm) * 136 + ch * 32 + lg * 8);
        b1[ch] = *(const f16x8*)(Xs + ((2 * w + 1) * 16 + lm) * 136 + ch * 32 + lg * 8);
    }

    // ---- stage Q: quadratic form. All 8 waves sweep i in phase: W_i (32KB)
    // is fetched into L1 once per CU per i. hx -> bbS in place (LDS).
    for (int i = 0; i < 16; ++i) {
        const _Float16* Wi = WBh + (size_t)i * 16384;
        f32x4 acc[2][8];
        #pragma unroll
        for (int tt = 0; tt < 2; ++tt)
            #pragma unroll
            for (int ft = 0; ft < 8; ++ft) acc[tt][ft] = (f32x4){0.f, 0.f, 0.f, 0.f};
        #pragma unroll
        for (int ch = 0; ch < 4; ++ch) {
            f16x8 af[8];
            #pragma unroll
            for (int ft = 0; ft < 8; ++ft)
                af[ft] = *(const f16x8*)(Wi + (ft * 4 + ch) * 512 + l * 8);
            #pragma unroll
            for (int ft = 0; ft < 8; ++ft) {
                acc[0][ft] = __builtin_amdgcn_mfma_f32_16x16x32_f16(af[ft], b0[ch], acc[0][ft], 0, 0, 0);
                acc[1][ft] = __builtin_amdgcn_mfma_f32_16x16x32_f16(af[ft], b1[ch], acc[1][ft], 0, 0, 0);
            }
        }
        // in-register contraction over f, then 2 shfl hops over lane groups
        #pragma unroll
        for (int tt = 0; tt < 2; ++tt) {
            int tok16 = (2 * w + tt) * 16;
            float part = 0.f;
            #pragma unroll
            for (int ft = 0; ft < 8; ++ft) {
                f16x4 xv = *(const f16x4*)(Xs + (tok16 + lm) * 136 + ft * 16 + lg * 4);
                part += acc[tt][ft][0] * (float)xv[0] + acc[tt][ft][1] * (float)xv[1]
                      + acc[tt][ft][2] * (float)xv[2] + acc[tt][ft][3] * (float)xv[3];
            }
            part += __shfl_xor(part, 16, 64);
            part += __shfl_xor(part, 32, 64);
            if (l < 16) {
                int t = tok16 + l;
                bbS[t * SST + i] = sigS[t * SST + i] * (part + bbS[t * SST + i]);
            }
        }
    }
    __syncthreads();

    // ---- flush hx (bbS) coalesced: 16 consecutive floats per token
    for (int idx = tid; idx < TM * 4; idx += 512) {
        int t = idx >> 2, g = (idx & 3) * 4;
        const float* hp = bbS + t * SST + g;
        *(float4*)(rec + (bt0 + t) * REC + 16 + g) =
            make_float4(hp[0], hp[1], hp[2], hp[3]);
    }
}

// ---------------------------------------------------------------------------
// Phase 2: sequence-parallel Kalman scan. Block = (b, chunk c). Chunk owns
// t in [c*CL, (c+1)*CL); warm-started WU steps early from generic init.
// Log-likelihood reduced via device-scope float atomics into out_sc[0..1]
// (zeroed by hipMemsetAsync before launch).
// ---------------------------------------------------------------------------
__global__ __launch_bounds__(64) void scan_kernel(
    const float* __restrict__ rec, const float* __restrict__ p0,
    float* __restrict__ out_ym, float* __restrict__ out_var,
    float* __restrict__ out_sc)
{
    const int blk = blockIdx.x;
    const int b   = blk / NC;
    const int c   = blk - b * NC;
    const int t0  = c * CL;                 // first owned step
    const int ts  = (c == 0) ? 0 : (t0 - WU);
    const int nst = t0 + CL - ts;           // total steps this block runs

    const int l  = threadIdx.x;
    const int d8 = l >> 3, c8 = l & 7;        // (row d, col-group) for CP/S/GJ
    const int i4 = l >> 2, j4 = (l & 3) * 4;  // (row i, col-block) for P stage

    __shared__ __align__(16) float Ps[2][REC];     // double-buffered record
    __shared__ __align__(16) float Pm[16 * 20];    // P, row stride 20 (padded)
    __shared__ __align__(16) float CPm[8 * 20];    // CP rows [d][m], stride 20
    __shared__ __align__(16) float CPT[16 * 12];   // CP^T rows [m][d], stride 12
    __shared__ __align__(16) float XT[16 * 12];    // X^T rows  [m][d], stride 12
    __shared__ __align__(16) float hS[NS];
    __shared__ __align__(16) float v8[DYV];

    // init: h = 0, P = diag(|p0|)  (exact for c==0; warmup-forgotten otherwise)
    {
        float pv = fabsf(p0[i4]);
        float4 t4;
        t4.x = (j4 + 0 == i4) ? pv : 0.f;  t4.y = (j4 + 1 == i4) ? pv : 0.f;
        t4.z = (j4 + 2 == i4) ? pv : 0.f;  t4.w = (j4 + 3 == i4) ? pv : 0.f;
        *(float4*)(Pm + i4 * 20 + j4) = t4;
        if (l < NS) hS[l] = 0.f;
    }
    const float4* rec4 = (const float4*)(rec + ((size_t)b * TSEQ + ts) * REC);
    float4 pf;
    if (l < 48) {
        ((float4*)Ps[0])[l] = rec4[l];     // record for first step
        pf = rec4[48 + l];                 // next record in flight
    }
    FENCE();

    float accll = 0.f;
    for (int k = 0; k < nst; ++k) {
        const int  t   = ts + k;
        const bool own = (t >= t0);
        const float* R_ = Ps[k & 1];
        float*       W_ = Ps[(k & 1) ^ 1];
        const int m0 = 2 * c8, m1 = m0 + 1;

        // ---- CP stage + folded y_pred.
        // cz[j] = C[d8][j]*ez[j]; yp = cz.h + C[d8].hx (all lanes, redundant)
        float cz[16];
        float4 c0, c1, c2, c3;
        {
            const float4* C4 = (const float4*)(R_ + 48 + 16 * d8);
            const float4* E4 = (const float4*)R_;
            c0 = C4[0]; c1 = C4[1]; c2 = C4[2]; c3 = C4[3];
            float4 e0 = E4[0], e1 = E4[1], e2 = E4[2], e3 = E4[3];
            cz[0]=c0.x*e0.x; cz[1]=c0.y*e0.y; cz[2]=c0.z*e0.z; cz[3]=c0.w*e0.w;
            cz[4]=c1.x*e1.x; cz[5]=c1.y*e1.y; cz[6]=c1.z*e1.z; cz[7]=c1.w*e1.w;
            cz[8]=c2.x*e2.x; cz[9]=c2.y*e2.y; cz[10]=c2.z*e2.z; cz[11]=c2.w*e2.w;
            cz[12]=c3.x*e3.x; cz[13]=c3.y*e3.y; cz[14]=c3.z*e3.z; cz[15]=c3.w*e3.w;
        }
        float e_save = 0.f;
        {
            const float4* H4 = (const float4*)hS;
            const float4* X4 = (const float4*)(R_ + 16);
            float4 h0=H4[0], h1=H4[1], h2=H4[2], h3=H4[3];
            float4 x0=X4[0], x1=X4[1], x2=X4[2], x3=X4[3];
            float yp = cz[0]*h0.x + cz[1]*h0.y + cz[2]*h0.z + cz[3]*h0.w
                     + cz[4]*h1.x + cz[5]*h1.y + cz[6]*h1.z + cz[7]*h1.w
                     + cz[8]*h2.x + cz[9]*h2.y + cz[10]*h2.z + cz[11]*h2.w
                     + cz[12]*h3.x + cz[13]*h3.y + cz[14]*h3.z + cz[15]*h3.w
                     + dot4_(c0, x0) + dot4_(c1, x1) + dot4_(c2, x2) + dot4_(c3, x3);
            if (c8 == 0) {
                e_save = R_[184 + d8] - yp;
                if (own) out_ym[((size_t)b * TSEQ + t) * 8 + d8] = yp;
            }
        }
        {
            float ezm0 = R_[m0],        ezm1 = R_[m1];
            float qm0  = R_[32 + m0],   qm1  = R_[32 + m1];
            float Cd0  = R_[48 + 16 * d8 + m0], Cd1 = R_[48 + 16 * d8 + m1];
            float cp0 = ezm0 * dot16a(cz, Pm + m0 * 20) + Cd0 * qm0;
            float cp1 = ezm1 * dot16a(cz, Pm + m1 * 20) + Cd1 * qm1;
            CPm[d8 * 20 + m0] = cp0;  CPm[d8 * 20 + m1] = cp1;
            CPT[m0 * 12 + d8] = cp0;  CPT[m1 * 12 + d8] = cp1;
        }
        float hpred_l = (l < NS) ? (R_[l] * hS[l] + R_[16 + l]) : 0.f;
        FENCE();

        // ---- S stage: augmented row [S(8) | CP(16) | e] distributed 4/lane
        float a0, a1, a2, a3;
        {
            const float4* CPr = (const float4*)(CPm + d8 * 20);
            const float4* Ce  = (const float4*)(R_ + 48 + 16 * c8);
            a0 = dot4_(CPr[0], Ce[0]) + dot4_(CPr[1], Ce[1])
               + dot4_(CPr[2], Ce[2]) + dot4_(CPr[3], Ce[3]);
            a1 = CPm[d8 * 20 + c8];
            a2 = CPm[d8 * 20 + c8 + 8];
            a3 = e_save;
            if (d8 == c8) {
                a0 += R_[176 + d8];
                if (own) out_var[((size_t)b * TSEQ + t) * 8 + d8] = a0;
            }
        }
        // stage next record + prefetch (independent of the chain)
        if (l < 48) {
            ((float4*)W_)[l] = pf;
            if (k + 2 < nst) pf = rec4[(size_t)(k + 2) * 48 + l];
        }
        FENCE();

        // ---- Gauss-Jordan on [S | CP | e]: ends as [I | X | v], det = prod piv
        // piv and b3 are uniform broadcasts from compile-time lanes -> readlane
        float pdet = 1.f;
        #pragma unroll
        for (int kk = 0; kk < 8; ++kk) {
            float piv = rdlane(a0, kk * 9);
            float b3  = rdlane(a3, kk * 8);
            float f_  = __shfl(a0, (d8 << 3) | kk, 64);
            float b0  = __shfl(a0, (kk << 3) | c8, 64);
            float b1  = __shfl(a1, (kk << 3) | c8, 64);
            float b2  = __shfl(a2, (kk << 3) | c8, 64);
            pdet *= piv;
            float ip = __builtin_amdgcn_rcpf(piv);
            ip = ip * (2.f - piv * ip);            // Newton: full fp32 rcp
            float fr = f_ * ip;
            if (d8 == kk) { a0 *= ip; a1 *= ip; a2 *= ip; a3 *= ip; }
            else          { a0 -= fr * b0; a1 -= fr * b1; a2 -= fr * b2; a3 -= fr * b3; }
        }

        // ---- publish X^T, v
        XT[c8 * 12 + d8]       = a1;
        XT[(c8 + 8) * 12 + d8] = a2;
        if (c8 == 0) v8[d8] = a3;
        FENCE();

        // log-likelihood (lanes c8==0 hold v[d8]; reduce over d8)
        {
            float qp = e_save * a3;
            qp += __shfl_xor(qp, 8, 64);
            qp += __shfl_xor(qp, 16, 64);
            qp += __shfl_xor(qp, 32, 64);
            if (l == 0 && own) accll += -0.5f * (logf(pdet) + qp + 8.f * LOG2PI_F);
        }
        // h_new (lanes 0..15): h = hpred + CP^T v
        if (l < NS) {
            const float4* ct = (const float4*)(CPT + l * 12);
            const float4* vv = (const float4*)v8;
            hS[l] = hpred_l + dot4_(ct[0], vv[0]) + dot4_(ct[1], vv[1]);
        }

        // ---- P_new = Ppred - CP^T X (symmetric in exact arithmetic)
        {
            const float4* ct = (const float4*)(CPT + i4 * 12);
            float4 ca = ct[0], cb = ct[1];
            float  ezi = R_[i4];
            float4 ezj = *(const float4*)(R_ + j4);
            float  qi  = R_[32 + i4];
            float4 po  = *(const float4*)(Pm + i4 * 20 + j4);
            float pol[4]  = {po.x, po.y, po.z, po.w};
            float ezjl[4] = {ezj.x, ezj.y, ezj.z, ezj.w};
            float pn[4];
            #pragma unroll
            for (int m = 0; m < 4; ++m) {
                int j = j4 + m;
                const float4* xt = (const float4*)(XT + j * 12);
                float dt = dot4_(ca, xt[0]) + dot4_(cb, xt[1]);
                float pp = ezi * ezjl[m] * pol[m] + ((j == i4) ? qi : 0.f);
                pn[m] = pp - dt;
            }
            *(float4*)(Pm + i4 * 20 + j4) = make_float4(pn[0], pn[1], pn[2], pn[3]);
        }
        FENCE();
    }
    if (l == 0) {
        atomicAdd(&out_sc[0], -accll / (float)NB);   // nll
        atomicAdd(&out_sc[1],  accll / (float)BT);   // avg_ll_per_step
    }
}

extern "C" void kernel_launch(void* const* d_in, const int* in_sizes, int n_in,
                              void* d_out, int out_size, void* d_ws, size_t ws_size,
                              hipStream_t stream) {
    const float* x     = (const float*)d_in[0];
    const float* y     = (const float*)d_in[1];
    const float* a_raw = (const float*)d_in[2];
    const float* Wg    = (const float*)d_in[3];
    const float* bg    = (const float*)d_in[4];
    const float* WBm   = (const float*)d_in[5];
    const float* bB    = (const float*)d_in[6];
    const float* WC    = (const float*)d_in[7];
    const float* bC    = (const float*)d_in[8];
    const float* Wsg   = (const float*)d_in[9];
    const float* bsg   = (const float*)d_in[10];
    const float* WR    = (const float*)d_in[11];
    const float* bR    = (const float*)d_in[12];
    const float* p0    = (const float*)d_in[13];

    float* rec   = (float*)d_ws;                        // 65536*192*4 = 50.3 MB
    _Float16* WBh = (_Float16*)(rec + (size_t)BT * REC); // 2048*128 fp16 swizzled
    _Float16* WHh = WBh + 2048 * 128;                   // 176*128 fp16 swizzled
    float* out   = (float*)d_out;
    float* out_sc = out + (size_t)2 * BT * DYV;         // [nll, avg_ll]

    hipMemsetAsync(out_sc, 0, 2 * sizeof(float), stream);
    prep_kernel<<<(2048 * 128 + 11 * 2048 + 255) / 256, 256, 0, stream>>>(
        WBm, Wg, Wsg, WR, WC, bB, WBh, WHh);
    proj_kernel<<<BT / TM, 512, 0, stream>>>(x, y, a_raw, bg, bsg, bR, bC,
                                             WBh, WHh, rec);
    scan_kernel<<<NB * NC, 64, 0, stream>>>(rec, p0, out, out + (size_t)BT * DYV,
                                            out_sc);
}

// Round 15
// 291.868 us; speedup vs baseline: 1.1887x; 1.0963x over previous
//
#include <hip/hip_runtime.h>
#include <math.h>

// ---------------------------------------------------------------------------
// ProbMambaHead: time-varying SSM + per-step Kalman filter.
// Phase 0 (prep_kernel): cast W_B + head weights to fp16, PRE-SWIZZLED into
//   MFMA fragment lane order.
// Phase 1 (proj_kernel): MFMA projections, TM=256 tokens/block, 512 thr
//   (8 waves, 1 block/CU): all waves sweep W_i in phase -> W_i fetched to L1
//   once per CU per i. hx written to LDS then flushed coalesced.
// Phase 2 (scan_kernel): sequence-parallel Kalman scan, 64 chunks x 32 owned
//   steps, 10-step warm-up. CL=32 = measured latency/DS-throughput balance.
//   hpred computed once into LDS (yp = C.hpred) -> -4 b128/wave-step.
//   llsum[blk] per block (NO same-address atomics: R14 showed 2048-block
//   same-address atomicAdd costs ~+33us) + tiny finalize kernel.
// Phase 3 (finalize_kernel): nll / avg_ll scalars.
// ---------------------------------------------------------------------------

#define FENCE() asm volatile("" ::: "memory")   // compiler-only fence; DS ops
// within one wave execute in order, so wave-synchronous LDS needs no barrier.

constexpr int NB   = 32;
constexpr int TSEQ = 2048;
constexpr int BT   = NB * TSEQ;   // 65536
constexpr int DF   = 128;
constexpr int NS   = 16;          // state dim n
constexpr int DYV  = 8;           // obs dim dy
constexpr int REC  = 192;         // floats per (b,t) record (48 float4)
constexpr int TM   = 256;         // tokens per proj block
constexpr int SST  = 17;          // sigS/bbS row stride (pad 16 -> 17)

constexpr int CL   = 32;          // owned steps per scan chunk (measured opt)
constexpr int WU   = 10;          // warmup steps
constexpr int NC   = TSEQ / CL;   // 64 chunks per batch

#define LOG2PI_F 1.8378770664093453f

typedef __attribute__((ext_vector_type(8))) _Float16 f16x8;
typedef __attribute__((ext_vector_type(4))) _Float16 f16x4;
typedef __attribute__((ext_vector_type(4))) float    f32x4;

__device__ __forceinline__ float sp_(float v) {          // jax.nn.softplus
    return v > 0.f ? v + log1pf(expf(-v)) : log1pf(expf(v));
}
__device__ __forceinline__ float dot4_(float4 a, float4 b) {
    return a.x*b.x + a.y*b.y + a.z*b.z + a.w*b.w;
}
__device__ __forceinline__ float dot16a(const float cz[16], const float* p) {
    const float4* p4 = (const float4*)p;
    float4 x0 = p4[0], x1 = p4[1], x2 = p4[2], x3 = p4[3];
    return cz[0]*x0.x + cz[1]*x0.y + cz[2]*x0.z + cz[3]*x0.w
         + cz[4]*x1.x + cz[5]*x1.y + cz[6]*x1.z + cz[7]*x1.w
         + cz[8]*x2.x + cz[9]*x2.y + cz[10]*x2.z + cz[11]*x2.w
         + cz[12]*x3.x + cz[13]*x3.y + cz[14]*x3.z + cz[15]*x3.w;
}
// uniform broadcast from a compile-time lane: scalar pipe, not DS
__device__ __forceinline__ float rdlane(float v, int lane) {
    return __int_as_float(__builtin_amdgcn_readlane(__float_as_int(v), lane));
}

// ---------------------------------------------------------------------------
// Phase 0: weight cast to fp16, swizzled into MFMA fragment lane order.
// WBh (A-fragment order): flat = i*16384 + p*512 + l*8 + j, p = ft*4+ch;
//   source = M_i[ft*16 + (l&15)][ch*32 + (l>>4)*8 + j].
// WHh (B-fragment order): flat = ((nt*4+ch)*64 + l)*8 + j;
//   head h = nt*16 + (l&15); k = ch*32 + (l>>4)*8 + j.
//   h<128: C row h | 128..143: sig | 144..151: R | 152: gate | 153..168: bB
//   | 169..175: zero.
// ---------------------------------------------------------------------------
__global__ __launch_bounds__(256) void prep_kernel(
    const float* __restrict__ WBm, const float* __restrict__ Wg,
    const float* __restrict__ Wsg, const float* __restrict__ WR,
    const float* __restrict__ WC,  const float* __restrict__ bB,
    _Float16* __restrict__ WBh, _Float16* __restrict__ WHh)
{
    int idx = blockIdx.x * 256 + threadIdx.x;
    if (idx < 2048 * 128) {
        int j = idx & 7, l = (idx >> 3) & 63, p = (idx >> 9) & 31, i = idx >> 14;
        int row = (p >> 2) * 16 + (l & 15);
        int col = (p & 3) * 32 + (l >> 4) * 8 + j;
        WBh[idx] = (_Float16)WBm[((size_t)i * 128 + row) * 128 + col];
        return;
    }
    idx -= 2048 * 128;
    if (idx >= 11 * 2048) return;            // 11 tiles * 4 * 64 * 8 = 22528
    int j = idx & 7, l = (idx >> 3) & 63, ch = (idx >> 9) & 3, nt = idx >> 11;
    int h = nt * 16 + (l & 15);
    int g = ch * 32 + (l >> 4) * 8 + j;
    float v;
    if (h < 128)       v = WC[h * 128 + g];
    else if (h < 144)  v = Wsg[(h - 128) * 128 + g];
    else if (h < 152)  v = WR[(h - 144) * 128 + g];
    else if (h == 152) v = Wg[g];
    else if (h < 169)  v = bB[(h - 153) * 128 + g];
    else               v = 0.f;
    WHh[idx] = (_Float16)v;
}

// ---------------------------------------------------------------------------
// Phase 1: MFMA projections. Block = 512 thr (8 waves), 256 tokens.
// Record layout: [0:16) exp_z | [16:32) hx | [32:48) q | [48:176) C (d*16+j)
//                | [176:184) R | [184:192) y.
// ---------------------------------------------------------------------------
__global__ __launch_bounds__(512) void proj_kernel(
    const float* __restrict__ x, const float* __restrict__ y,
    const float* __restrict__ a_raw,
    const float* __restrict__ bg, const float* __restrict__ bsg,
    const float* __restrict__ bR, const float* __restrict__ bC,
    const _Float16* __restrict__ WBh, const _Float16* __restrict__ WHh,
    float* __restrict__ rec)
{
    __shared__ __align__(16) _Float16 Xs[TM * 136];   // [tok][f] fp16, pad 136
    __shared__ __align__(16) float Dsh[TM];           // Delta
    __shared__ __align__(16) float sigS[TM * SST];    // sigma -> gamma*Delta
    __shared__ __align__(16) float bbS[TM * SST];     // bB.x -> (stage Q) hx

    const int tid = threadIdx.x;
    const long bt0 = (long)blockIdx.x * TM;
    const int l  = tid & 63, w = tid >> 6;            // w in [0,8)
    const int lm = l & 15,  lg = l >> 4;

    // ---- stage X: load fp32 tile -> fp16 LDS; y -> rec
    {
        const float4* x4 = (const float4*)(x + bt0 * DF);
        #pragma unroll
        for (int k = 0; k < 16; ++k) {
            int idx = tid + k * 512;           // 8192 float4 = 256x128
            int tok = idx >> 5, fg = idx & 31;
            float4 v = x4[idx];
            f16x4 hv = { (_Float16)v.x, (_Float16)v.y, (_Float16)v.z, (_Float16)v.w };
            *(f16x4*)(Xs + tok * 136 + fg * 4) = hv;
        }
        float4 yv = ((const float4*)(y + bt0 * DYV))[tid];   // 512 float4
        *(float4*)(rec + (bt0 + (tid >> 1)) * REC + 184 + (tid & 1) * 4) = yv;
    }
    __syncthreads();

    // ---- stage H: head GEMM, wave w owns token-tiles {2w, 2w+1}.
    for (int nt = 0; nt < 11; ++nt) {
        f16x8 wf[4];
        #pragma unroll
        for (int ch = 0; ch < 4; ++ch)
            wf[ch] = *(const f16x8*)(WHh + ((nt * 4 + ch) * 64 + l) * 8);
        #pragma unroll
        for (int tt2 = 0; tt2 < 2; ++tt2) {
            const int tt = 2 * w + tt2;
            f32x4 acc = {0.f, 0.f, 0.f, 0.f};
            #pragma unroll
            for (int ch = 0; ch < 4; ++ch) {
                f16x8 xf = *(const f16x8*)(Xs + (tt * 16 + lm) * 136 + ch * 32 + lg * 8);
                acc = __builtin_amdgcn_mfma_f32_16x16x32_f16(xf, wf[ch], acc, 0, 0, 0);
            }
            const int tokb = tt * 16 + lg * 4;           // + reg
            if (nt < 8) {                                // pure C tiles
                float bias = bC[nt * 16 + lm];
                #pragma unroll
                for (int rg = 0; rg < 4; ++rg)
                    rec[(bt0 + tokb + rg) * REC + 48 + nt * 16 + lm] = acc[rg] + bias;
            } else if (nt == 8) {                        // pure sig tile
                float bias = bsg[lm];
                #pragma unroll
                for (int rg = 0; rg < 4; ++rg)
                    sigS[(tokb + rg) * SST + lm] = sp_(acc[rg] + bias) + 1e-6f + 1e-3f;
            } else if (nt == 9) {                        // R | gate | bB 0..6
                #pragma unroll
                for (int rg = 0; rg < 4; ++rg) {
                    int tok = tokb + rg; float v = acc[rg];
                    if (lm < 8)
                        rec[(bt0 + tok) * REC + 176 + lm] = sp_(v + bR[lm]) + 1e-6f + 1e-4f;
                    else if (lm == 8)
                        Dsh[tok] = fminf(fmaxf(sp_(v + bg[0]) + 1e-6f, 1e-3f), 1.0f);
                    else
                        bbS[tok * SST + (lm - 9)] = v;
                }
            } else {                                     // bB 7..15 | pad
                #pragma unroll
                for (int rg = 0; rg < 4; ++rg)
                    if (lm < 9) bbS[(tokb + rg) * SST + 7 + lm] = acc[rg];
            }
        }
    }
    __syncthreads();

    // ---- stage Z: per (t,i) ez/q; sigS becomes gamma*Delta in place
    for (int p = tid; p < TM * NS; p += 512) {
        int t = p >> 4, i = p & 15;
        float D  = Dsh[t];
        float a  = -(sp_(a_raw[i]) + 1e-6f);
        float z  = fminf(fmaxf(D * a, -20.f), 20.f);
        float ez = expf(z);
        float gam = (fabsf(z) < 1e-4f) ? (1.f + 0.5f * z) : (expm1f(z) / z);
        float z2  = 2.f * z;
        float rho = (fabsf(z2) < 1e-4f) ? (1.f + 0.5f * z2) : (expm1f(z2) / z2);
        float sg  = sigS[t * SST + i];
        long base = (bt0 + t) * REC;
        rec[base + i]      = ez;
        rec[base + 32 + i] = sg * sg * rho * D;
        sigS[t * SST + i] = gam * D;             // now gamma*Delta
    }
    __syncthreads();                             // sigS/bbS ready for epilogue

    // ---- hoist B-fragments (loop-invariant over i): wave w's tokens
    f16x8 b0[4], b1[4];
    #pragma unroll
    for (int ch = 0; ch < 4; ++ch) {
        b0[ch] = *(const f16x8*)(Xs + ((2 * w) * 16 + lm) * 136 + ch * 32 + lg * 8);
        b1[ch] = *(const f16x8*)(Xs + ((2 * w + 1) * 16 + lm) * 136 + ch * 32 + lg * 8);
    }

    // ---- stage Q: quadratic form. All 8 waves sweep i in phase: W_i (32KB)
    // is fetched into L1 once per CU per i. hx -> bbS in place (LDS).
    for (int i = 0; i < 16; ++i) {
        const _Float16* Wi = WBh + (size_t)i * 16384;
        f32x4 acc[2][8];
        #pragma unroll
        for (int tt = 0; tt < 2; ++tt)
            #pragma unroll
            for (int ft = 0; ft < 8; ++ft) acc[tt][ft] = (f32x4){0.f, 0.f, 0.f, 0.f};
        #pragma unroll
        for (int ch = 0; ch < 4; ++ch) {
            f16x8 af[8];
            #pragma unroll
            for (int ft = 0; ft < 8; ++ft)
                af[ft] = *(const f16x8*)(Wi + (ft * 4 + ch) * 512 + l * 8);
            #pragma unroll
            for (int ft = 0; ft < 8; ++ft) {
                acc[0][ft] = __builtin_amdgcn_mfma_f32_16x16x32_f16(af[ft], b0[ch], acc[0][ft], 0, 0, 0);
                acc[1][ft] = __builtin_amdgcn_mfma_f32_16x16x32_f16(af[ft], b1[ch], acc[1][ft], 0, 0, 0);
            }
        }
        // in-register contraction over f, then 2 shfl hops over lane groups
        #pragma unroll
        for (int tt = 0; tt < 2; ++tt) {
            int tok16 = (2 * w + tt) * 16;
            float part = 0.f;
            #pragma unroll
            for (int ft = 0; ft < 8; ++ft) {
                f16x4 xv = *(const f16x4*)(Xs + (tok16 + lm) * 136 + ft * 16 + lg * 4);
                part += acc[tt][ft][0] * (float)xv[0] + acc[tt][ft][1] * (float)xv[1]
                      + acc[tt][ft][2] * (float)xv[2] + acc[tt][ft][3] * (float)xv[3];
            }
            part += __shfl_xor(part, 16, 64);
            part += __shfl_xor(part, 32, 64);
            if (l < 16) {
                int t = tok16 + l;
                bbS[t * SST + i] = sigS[t * SST + i] * (part + bbS[t * SST + i]);
            }
        }
    }
    __syncthreads();

    // ---- flush hx (bbS) coalesced: 16 consecutive floats per token
    for (int idx = tid; idx < TM * 4; idx += 512) {
        int t = idx >> 2, g = (idx & 3) * 4;
        const float* hp = bbS + t * SST + g;
        *(float4*)(rec + (bt0 + t) * REC + 16 + g) =
            make_float4(hp[0], hp[1], hp[2], hp[3]);
    }
}

// ---------------------------------------------------------------------------
// Phase 2: sequence-parallel Kalman scan. Block = (b, chunk c). Chunk owns
// t in [c*CL, (c+1)*CL); warm-started WU steps early from generic init.
// ---------------------------------------------------------------------------
__global__ __launch_bounds__(64) void scan_kernel(
    const float* __restrict__ rec, const float* __restrict__ p0,
    float* __restrict__ out_ym, float* __restrict__ out_var,
    float* __restrict__ llsum)
{
    const int blk = blockIdx.x;
    const int b   = blk / NC;
    const int c   = blk - b * NC;
    const int t0  = c * CL;                 // first owned step
    const int ts  = (c == 0) ? 0 : (t0 - WU);
    const int nst = t0 + CL - ts;           // total steps this block runs

    const int l  = threadIdx.x;
    const int d8 = l >> 3, c8 = l & 7;        // (row d, col-group) for CP/S/GJ
    const int i4 = l >> 2, j4 = (l & 3) * 4;  // (row i, col-block) for P stage

    __shared__ __align__(16) float Ps[2][REC];     // double-buffered record
    __shared__ __align__(16) float Pm[16 * 20];    // P, row stride 20 (padded)
    __shared__ __align__(16) float CPm[8 * 20];    // CP rows [d][m], stride 20
    __shared__ __align__(16) float CPT[16 * 12];   // CP^T rows [m][d], stride 12
    __shared__ __align__(16) float XT[16 * 12];    // X^T rows  [m][d], stride 12
    __shared__ __align__(16) float hS[NS];
    __shared__ __align__(16) float hpredS[NS];
    __shared__ __align__(16) float v8[DYV];

    // init: h = 0, P = diag(|p0|)  (exact for c==0; warmup-forgotten otherwise)
    {
        float pv = fabsf(p0[i4]);
        float4 t4;
        t4.x = (j4 + 0 == i4) ? pv : 0.f;  t4.y = (j4 + 1 == i4) ? pv : 0.f;
        t4.z = (j4 + 2 == i4) ? pv : 0.f;  t4.w = (j4 + 3 == i4) ? pv : 0.f;
        *(float4*)(Pm + i4 * 20 + j4) = t4;
        if (l < NS) hS[l] = 0.f;
    }
    const float4* rec4 = (const float4*)(rec + ((size_t)b * TSEQ + ts) * REC);
    float4 pf;
    if (l < 48) {
        ((float4*)Ps[0])[l] = rec4[l];     // record for first step
        pf = rec4[48 + l];                 // next record in flight
    }
    FENCE();

    float accll = 0.f;
    for (int k = 0; k < nst; ++k) {
        const int  t   = ts + k;
        const bool own = (t >= t0);
        const float* R_ = Ps[k & 1];
        float*       W_ = Ps[(k & 1) ^ 1];
        const int m0 = 2 * c8, m1 = m0 + 1;

        // ---- hpred = ez*h + hx (lanes 0..15) -> LDS; yp uses C.hpred
        if (l < NS) hpredS[l] = R_[l] * hS[l] + R_[16 + l];
        FENCE();

        // ---- CP stage + folded y_pred.
        float cz[16];
        float4 c0, c1, c2, c3;
        {
            const float4* C4 = (const float4*)(R_ + 48 + 16 * d8);
            const float4* E4 = (const float4*)R_;
            c0 = C4[0]; c1 = C4[1]; c2 = C4[2]; c3 = C4[3];
            float4 e0 = E4[0], e1 = E4[1], e2 = E4[2], e3 = E4[3];
            cz[0]=c0.x*e0.x; cz[1]=c0.y*e0.y; cz[2]=c0.z*e0.z; cz[3]=c0.w*e0.w;
            cz[4]=c1.x*e1.x; cz[5]=c1.y*e1.y; cz[6]=c1.z*e1.z; cz[7]=c1.w*e1.w;
            cz[8]=c2.x*e2.x; cz[9]=c2.y*e2.y; cz[10]=c2.z*e2.z; cz[11]=c2.w*e2.w;
            cz[12]=c3.x*e3.x; cz[13]=c3.y*e3.y; cz[14]=c3.z*e3.z; cz[15]=c3.w*e3.w;
        }
        float e_save = 0.f;
        {
            const float4* HP = (const float4*)hpredS;
            float yp = dot4_(c0, HP[0]) + dot4_(c1, HP[1])
                     + dot4_(c2, HP[2]) + dot4_(c3, HP[3]);
            if (c8 == 0) {
                e_save = R_[184 + d8] - yp;
                if (own) out_ym[((size_t)b * TSEQ + t) * 8 + d8] = yp;
            }
        }
        {
            float ezm0 = R_[m0],        ezm1 = R_[m1];
            float qm0  = R_[32 + m0],   qm1  = R_[32 + m1];
            float Cd0  = R_[48 + 16 * d8 + m0], Cd1 = R_[48 + 16 * d8 + m1];
            float cp0 = ezm0 * dot16a(cz, Pm + m0 * 20) + Cd0 * qm0;
            float cp1 = ezm1 * dot16a(cz, Pm + m1 * 20) + Cd1 * qm1;
            CPm[d8 * 20 + m0] = cp0;  CPm[d8 * 20 + m1] = cp1;
            CPT[m0 * 12 + d8] = cp0;  CPT[m1 * 12 + d8] = cp1;
        }
        FENCE();

        // ---- S stage: augmented row [S(8) | CP(16) | e] distributed 4/lane
        float a0, a1, a2, a3;
        {
            const float4* CPr = (const float4*)(CPm + d8 * 20);
            const float4* Ce  = (const float4*)(R_ + 48 + 16 * c8);
            a0 = dot4_(CPr[0], Ce[0]) + dot4_(CPr[1], Ce[1])
               + dot4_(CPr[2], Ce[2]) + dot4_(CPr[3], Ce[3]);
            a1 = CPm[d8 * 20 + c8];
            a2 = CPm[d8 * 20 + c8 + 8];
            a3 = e_save;
            if (d8 == c8) {
                a0 += R_[176 + d8];
                if (own) out_var[((size_t)b * TSEQ + t) * 8 + d8] = a0;
            }
        }
        // stage next record + prefetch (independent of the chain)
        if (l < 48) {
            ((float4*)W_)[l] = pf;
            if (k + 2 < nst) pf = rec4[(size_t)(k + 2) * 48 + l];
        }
        FENCE();

        // ---- Gauss-Jordan on [S | CP | e]: ends as [I | X | v], det = prod piv
        // piv and b3 are uniform broadcasts from compile-time lanes -> readlane
        float pdet = 1.f;
        #pragma unroll
        for (int kk = 0; kk < 8; ++kk) {
            float piv = rdlane(a0, kk * 9);
            float b3  = rdlane(a3, kk * 8);
            float f_  = __shfl(a0, (d8 << 3) | kk, 64);
            float b0  = __shfl(a0, (kk << 3) | c8, 64);
            float b1  = __shfl(a1, (kk << 3) | c8, 64);
            float b2  = __shfl(a2, (kk << 3) | c8, 64);
            pdet *= piv;
            float ip = __builtin_amdgcn_rcpf(piv);
            ip = ip * (2.f - piv * ip);            // Newton: full fp32 rcp
            float fr = f_ * ip;
            if (d8 == kk) { a0 *= ip; a1 *= ip; a2 *= ip; a3 *= ip; }
            else          { a0 -= fr * b0; a1 -= fr * b1; a2 -= fr * b2; a3 -= fr * b3; }
        }

        // ---- publish X^T, v
        XT[c8 * 12 + d8]       = a1;
        XT[(c8 + 8) * 12 + d8] = a2;
        if (c8 == 0) v8[d8] = a3;
        FENCE();

        // log-likelihood (lanes c8==0 hold v[d8]; reduce over d8)
        {
            float qp = e_save * a3;
            qp += __shfl_xor(qp, 8, 64);
            qp += __shfl_xor(qp, 16, 64);
            qp += __shfl_xor(qp, 32, 64);
            if (l == 0 && own) accll += -0.5f * (logf(pdet) + qp + 8.f * LOG2PI_F);
        }
        // h_new (lanes 0..15): h = hpred + CP^T v
        if (l < NS) {
            const float4* ct = (const float4*)(CPT + l * 12);
            const float4* vv = (const float4*)v8;
            hS[l] = hpredS[l] + dot4_(ct[0], vv[0]) + dot4_(ct[1], vv[1]);
        }

        // ---- P_new = Ppred - CP^T X (symmetric in exact arithmetic)
        {
            const float4* ct = (const float4*)(CPT + i4 * 12);
            float4 ca = ct[0], cb = ct[1];
            float  ezi = R_[i4];
            float4 ezj = *(const float4*)(R_ + j4);
            float  qi  = R_[32 + i4];
            float4 po  = *(const float4*)(Pm + i4 * 20 + j4);
            float pol[4]  = {po.x, po.y, po.z, po.w};
            float ezjl[4] = {ezj.x, ezj.y, ezj.z, ezj.w};
            float pn[4];
            #pragma unroll
            for (int m = 0; m < 4; ++m) {
                int j = j4 + m;
                const float4* xt = (const float4*)(XT + j * 12);
                float dt = dot4_(ca, xt[0]) + dot4_(cb, xt[1]);
                float pp = ezi * ezjl[m] * pol[m] + ((j == i4) ? qi : 0.f);
                pn[m] = pp - dt;
            }
            *(float4*)(Pm + i4 * 20 + j4) = make_float4(pn[0], pn[1], pn[2], pn[3]);
        }
        FENCE();
    }
    if (l == 0) llsum[blk] = accll;
}

// ---------------------------------------------------------------------------
// Phase 3: scalars (sum NB*NC partial ll sums)
// ---------------------------------------------------------------------------
__global__ void finalize_kernel(const float* __restrict__ llsum,
                                float* __restrict__ out)
{
    if (blockIdx.x != 0) return;
    int l = threadIdx.x;
    float s = 0.f;
    for (int i = l; i < NB * NC; i += 64) s += llsum[i];
    #pragma unroll
    for (int off = 1; off < 64; off <<= 1) s += __shfl_xor(s, off, 64);
    if (l == 0) {
        out[(size_t)2 * BT * DYV]     = -s / (float)NB;        // nll
        out[(size_t)2 * BT * DYV + 1] =  s / (float)BT;        // avg_ll_per_step
    }
}

extern "C" void kernel_launch(void* const* d_in, const int* in_sizes, int n_in,
                              void* d_out, int out_size, void* d_ws, size_t ws_size,
                              hipStream_t stream) {
    const float* x     = (const float*)d_in[0];
    const float* y     = (const float*)d_in[1];
    const float* a_raw = (const float*)d_in[2];
    const float* Wg    = (const float*)d_in[3];
    const float* bg    = (const float*)d_in[4];
    const float* WBm   = (const float*)d_in[5];
    const float* bB    = (const float*)d_in[6];
    const float* WC    = (const float*)d_in[7];
    const float* bC    = (const float*)d_in[8];
    const float* Wsg   = (const float*)d_in[9];
    const float* bsg   = (const float*)d_in[10];
    const float* WR    = (const float*)d_in[11];
    const float* bR    = (const float*)d_in[12];
    const float* p0    = (const float*)d_in[13];

    float* rec   = (float*)d_ws;                        // 65536*192*4 = 50.3 MB
    float* llsum = rec + (size_t)BT * REC;              // + NB*NC floats
    _Float16* WBh = (_Float16*)(llsum + NB * NC);       // 2048*128 fp16 swizzled
    _Float16* WHh = WBh + 2048 * 128;                   // 176*128 fp16 swizzled
    float* out   = (float*)d_out;

    prep_kernel<<<(2048 * 128 + 11 * 2048 + 255) / 256, 256, 0, stream>>>(
        WBm, Wg, Wsg, WR, WC, bB, WBh, WHh);
    proj_kernel<<<BT / TM, 512, 0, stream>>>(x, y, a_raw, bg, bsg, bR, bC,
                                             WBh, WHh, rec);
    scan_kernel<<<NB * NC, 64, 0, stream>>>(rec, p0, out, out + (size_t)BT * DYV,
                                            llsum);
    finalize_kernel<<<1, 64, 0, stream>>>(llsum, out);
}

// Round 16
// 289.216 us; speedup vs baseline: 1.1996x; 1.0092x over previous
//
#include <hip/hip_runtime.h>
#include <math.h>

// ---------------------------------------------------------------------------
// ProbMambaHead: time-varying SSM + per-step Kalman filter.
// Phase 0 (prep_kernel): cast W_B + head weights to fp16, PRE-SWIZZLED into
//   MFMA fragment lane order.
// Phase 1 (proj_kernel): MFMA projections, TM=256 tokens/block, 512 thr
//   (8 waves, 1 block/CU): all waves sweep W_i in phase -> W_i fetched to L1
//   once per CU per i. xv contraction fragments hoisted out of the i-loop
//   (they are i-invariant: -256 DS reads/wave). hx flushed coalesced.
// Phase 2 (scan_kernel): sequence-parallel Kalman scan, 64 chunks x 32 owned
//   steps, 9-step warm-up. CL=32 = measured latency/DS-throughput balance.
//   llsum[blk] per block (no same-address atomics) + tiny finalize kernel.
// Phase 3 (finalize_kernel): nll / avg_ll scalars.
// ---------------------------------------------------------------------------

#define FENCE() asm volatile("" ::: "memory")   // compiler-only fence; DS ops
// within one wave execute in order, so wave-synchronous LDS needs no barrier.

constexpr int NB   = 32;
constexpr int TSEQ = 2048;
constexpr int BT   = NB * TSEQ;   // 65536
constexpr int DF   = 128;
constexpr int NS   = 16;          // state dim n
constexpr int DYV  = 8;           // obs dim dy
constexpr int REC  = 192;         // floats per (b,t) record (48 float4)
constexpr int TM   = 256;         // tokens per proj block
constexpr int SST  = 17;          // sigS/bbS row stride (pad 16 -> 17)

constexpr int CL   = 32;          // owned steps per scan chunk (measured opt)
constexpr int WU   = 9;           // warmup steps
constexpr int NC   = TSEQ / CL;   // 64 chunks per batch

#define LOG2PI_F 1.8378770664093453f

typedef __attribute__((ext_vector_type(8))) _Float16 f16x8;
typedef __attribute__((ext_vector_type(4))) _Float16 f16x4;
typedef __attribute__((ext_vector_type(4))) float    f32x4;

__device__ __forceinline__ float sp_(float v) {          // jax.nn.softplus
    return v > 0.f ? v + log1pf(expf(-v)) : log1pf(expf(v));
}
__device__ __forceinline__ float dot4_(float4 a, float4 b) {
    return a.x*b.x + a.y*b.y + a.z*b.z + a.w*b.w;
}
__device__ __forceinline__ float dot16a(const float cz[16], const float* p) {
    const float4* p4 = (const float4*)p;
    float4 x0 = p4[0], x1 = p4[1], x2 = p4[2], x3 = p4[3];
    return cz[0]*x0.x + cz[1]*x0.y + cz[2]*x0.z + cz[3]*x0.w
         + cz[4]*x1.x + cz[5]*x1.y + cz[6]*x1.z + cz[7]*x1.w
         + cz[8]*x2.x + cz[9]*x2.y + cz[10]*x2.z + cz[11]*x2.w
         + cz[12]*x3.x + cz[13]*x3.y + cz[14]*x3.z + cz[15]*x3.w;
}
// uniform broadcast from a compile-time lane: scalar pipe, not DS
__device__ __forceinline__ float rdlane(float v, int lane) {
    return __int_as_float(__builtin_amdgcn_readlane(__float_as_int(v), lane));
}

// ---------------------------------------------------------------------------
// Phase 0: weight cast to fp16, swizzled into MFMA fragment lane order.
// WBh (A-fragment order): flat = i*16384 + p*512 + l*8 + j, p = ft*4+ch;
//   source = M_i[ft*16 + (l&15)][ch*32 + (l>>4)*8 + j].
// WHh (B-fragment order): flat = ((nt*4+ch)*64 + l)*8 + j;
//   head h = nt*16 + (l&15); k = ch*32 + (l>>4)*8 + j.
//   h<128: C row h | 128..143: sig | 144..151: R | 152: gate | 153..168: bB
//   | 169..175: zero.
// ---------------------------------------------------------------------------
__global__ __launch_bounds__(256) void prep_kernel(
    const float* __restrict__ WBm, const float* __restrict__ Wg,
    const float* __restrict__ Wsg, const float* __restrict__ WR,
    const float* __restrict__ WC,  const float* __restrict__ bB,
    _Float16* __restrict__ WBh, _Float16* __restrict__ WHh)
{
    int idx = blockIdx.x * 256 + threadIdx.x;
    if (idx < 2048 * 128) {
        int j = idx & 7, l = (idx >> 3) & 63, p = (idx >> 9) & 31, i = idx >> 14;
        int row = (p >> 2) * 16 + (l & 15);
        int col = (p & 3) * 32 + (l >> 4) * 8 + j;
        WBh[idx] = (_Float16)WBm[((size_t)i * 128 + row) * 128 + col];
        return;
    }
    idx -= 2048 * 128;
    if (idx >= 11 * 2048) return;            // 11 tiles * 4 * 64 * 8 = 22528
    int j = idx & 7, l = (idx >> 3) & 63, ch = (idx >> 9) & 3, nt = idx >> 11;
    int h = nt * 16 + (l & 15);
    int g = ch * 32 + (l >> 4) * 8 + j;
    float v;
    if (h < 128)       v = WC[h * 128 + g];
    else if (h < 144)  v = Wsg[(h - 128) * 128 + g];
    else if (h < 152)  v = WR[(h - 144) * 128 + g];
    else if (h == 152) v = Wg[g];
    else if (h < 169)  v = bB[(h - 153) * 128 + g];
    else               v = 0.f;
    WHh[idx] = (_Float16)v;
}

// ---------------------------------------------------------------------------
// Phase 1: MFMA projections. Block = 512 thr (8 waves), 256 tokens.
// Record layout: [0:16) exp_z | [16:32) hx | [32:48) q | [48:176) C (d*16+j)
//                | [176:184) R | [184:192) y.
// ---------------------------------------------------------------------------
__global__ __launch_bounds__(512) void proj_kernel(
    const float* __restrict__ x, const float* __restrict__ y,
    const float* __restrict__ a_raw,
    const float* __restrict__ bg, const float* __restrict__ bsg,
    const float* __restrict__ bR, const float* __restrict__ bC,
    const _Float16* __restrict__ WBh, const _Float16* __restrict__ WHh,
    float* __restrict__ rec)
{
    __shared__ __align__(16) _Float16 Xs[TM * 136];   // [tok][f] fp16, pad 136
    __shared__ __align__(16) float Dsh[TM];           // Delta
    __shared__ __align__(16) float sigS[TM * SST];    // sigma -> gamma*Delta
    __shared__ __align__(16) float bbS[TM * SST];     // bB.x -> (stage Q) hx

    const int tid = threadIdx.x;
    const long bt0 = (long)blockIdx.x * TM;
    const int l  = tid & 63, w = tid >> 6;            // w in [0,8)
    const int lm = l & 15,  lg = l >> 4;

    // ---- stage X: load fp32 tile -> fp16 LDS; y -> rec
    {
        const float4* x4 = (const float4*)(x + bt0 * DF);
        #pragma unroll
        for (int k = 0; k < 16; ++k) {
            int idx = tid + k * 512;           // 8192 float4 = 256x128
            int tok = idx >> 5, fg = idx & 31;
            float4 v = x4[idx];
            f16x4 hv = { (_Float16)v.x, (_Float16)v.y, (_Float16)v.z, (_Float16)v.w };
            *(f16x4*)(Xs + tok * 136 + fg * 4) = hv;
        }
        float4 yv = ((const float4*)(y + bt0 * DYV))[tid];   // 512 float4
        *(float4*)(rec + (bt0 + (tid >> 1)) * REC + 184 + (tid & 1) * 4) = yv;
    }
    __syncthreads();

    // ---- stage H: head GEMM, wave w owns token-tiles {2w, 2w+1}.
    for (int nt = 0; nt < 11; ++nt) {
        f16x8 wf[4];
        #pragma unroll
        for (int ch = 0; ch < 4; ++ch)
            wf[ch] = *(const f16x8*)(WHh + ((nt * 4 + ch) * 64 + l) * 8);
        #pragma unroll
        for (int tt2 = 0; tt2 < 2; ++tt2) {
            const int tt = 2 * w + tt2;
            f32x4 acc = {0.f, 0.f, 0.f, 0.f};
            #pragma unroll
            for (int ch = 0; ch < 4; ++ch) {
                f16x8 xf = *(const f16x8*)(Xs + (tt * 16 + lm) * 136 + ch * 32 + lg * 8);
                acc = __builtin_amdgcn_mfma_f32_16x16x32_f16(xf, wf[ch], acc, 0, 0, 0);
            }
            const int tokb = tt * 16 + lg * 4;           // + reg
            if (nt < 8) {                                // pure C tiles
                float bias = bC[nt * 16 + lm];
                #pragma unroll
                for (int rg = 0; rg < 4; ++rg)
                    rec[(bt0 + tokb + rg) * REC + 48 + nt * 16 + lm] = acc[rg] + bias;
            } else if (nt == 8) {                        // pure sig tile
                float bias = bsg[lm];
                #pragma unroll
                for (int rg = 0; rg < 4; ++rg)
                    sigS[(tokb + rg) * SST + lm] = sp_(acc[rg] + bias) + 1e-6f + 1e-3f;
            } else if (nt == 9) {                        // R | gate | bB 0..6
                #pragma unroll
                for (int rg = 0; rg < 4; ++rg) {
                    int tok = tokb + rg; float v = acc[rg];
                    if (lm < 8)
                        rec[(bt0 + tok) * REC + 176 + lm] = sp_(v + bR[lm]) + 1e-6f + 1e-4f;
                    else if (lm == 8)
                        Dsh[tok] = fminf(fmaxf(sp_(v + bg[0]) + 1e-6f, 1e-3f), 1.0f);
                    else
                        bbS[tok * SST + (lm - 9)] = v;
                }
            } else {                                     // bB 7..15 | pad
                #pragma unroll
                for (int rg = 0; rg < 4; ++rg)
                    if (lm < 9) bbS[(tokb + rg) * SST + 7 + lm] = acc[rg];
            }
        }
    }
    __syncthreads();

    // ---- stage Z: per (t,i) ez/q; sigS becomes gamma*Delta in place
    for (int p = tid; p < TM * NS; p += 512) {
        int t = p >> 4, i = p & 15;
        float D  = Dsh[t];
        float a  = -(sp_(a_raw[i]) + 1e-6f);
        float z  = fminf(fmaxf(D * a, -20.f), 20.f);
        float ez = expf(z);
        float gam = (fabsf(z) < 1e-4f) ? (1.f + 0.5f * z) : (expm1f(z) / z);
        float z2  = 2.f * z;
        float rho = (fabsf(z2) < 1e-4f) ? (1.f + 0.5f * z2) : (expm1f(z2) / z2);
        float sg  = sigS[t * SST + i];
        long base = (bt0 + t) * REC;
        rec[base + i]      = ez;
        rec[base + 32 + i] = sg * sg * rho * D;
        sigS[t * SST + i] = gam * D;             // now gamma*Delta
    }
    __syncthreads();                             // sigS/bbS ready for epilogue

    // ---- hoist B-fragments and xv contraction fragments (i-invariant)
    f16x8 b0[4], b1[4];
    f16x4 xv0[8], xv1[8];
    #pragma unroll
    for (int ch = 0; ch < 4; ++ch) {
        b0[ch] = *(const f16x8*)(Xs + ((2 * w) * 16 + lm) * 136 + ch * 32 + lg * 8);
        b1[ch] = *(const f16x8*)(Xs + ((2 * w + 1) * 16 + lm) * 136 + ch * 32 + lg * 8);
    }
    #pragma unroll
    for (int ft = 0; ft < 8; ++ft) {
        xv0[ft] = *(const f16x4*)(Xs + ((2 * w) * 16 + lm) * 136 + ft * 16 + lg * 4);
        xv1[ft] = *(const f16x4*)(Xs + ((2 * w + 1) * 16 + lm) * 136 + ft * 16 + lg * 4);
    }

    // ---- stage Q: quadratic form. All 8 waves sweep i in phase: W_i (32KB)
    // is fetched into L1 once per CU per i. hx -> bbS in place (LDS).
    for (int i = 0; i < 16; ++i) {
        const _Float16* Wi = WBh + (size_t)i * 16384;
        f32x4 acc[2][8];
        #pragma unroll
        for (int tt = 0; tt < 2; ++tt)
            #pragma unroll
            for (int ft = 0; ft < 8; ++ft) acc[tt][ft] = (f32x4){0.f, 0.f, 0.f, 0.f};
        #pragma unroll
        for (int ch = 0; ch < 4; ++ch) {
            f16x8 af[8];
            #pragma unroll
            for (int ft = 0; ft < 8; ++ft)
                af[ft] = *(const f16x8*)(Wi + (ft * 4 + ch) * 512 + l * 8);
            #pragma unroll
            for (int ft = 0; ft < 8; ++ft) {
                acc[0][ft] = __builtin_amdgcn_mfma_f32_16x16x32_f16(af[ft], b0[ch], acc[0][ft], 0, 0, 0);
                acc[1][ft] = __builtin_amdgcn_mfma_f32_16x16x32_f16(af[ft], b1[ch], acc[1][ft], 0, 0, 0);
            }
        }
        // in-register contraction over f (xv hoisted), then 2 shfl hops
        #pragma unroll
        for (int tt = 0; tt < 2; ++tt) {
            const f16x4* xv = tt ? xv1 : xv0;
            float part = 0.f;
            #pragma unroll
            for (int ft = 0; ft < 8; ++ft) {
                part += acc[tt][ft][0] * (float)xv[ft][0] + acc[tt][ft][1] * (float)xv[ft][1]
                      + acc[tt][ft][2] * (float)xv[ft][2] + acc[tt][ft][3] * (float)xv[ft][3];
            }
            part += __shfl_xor(part, 16, 64);
            part += __shfl_xor(part, 32, 64);
            if (l < 16) {
                int t = (2 * w + tt) * 16 + l;
                bbS[t * SST + i] = sigS[t * SST + i] * (part + bbS[t * SST + i]);
            }
        }
    }
    __syncthreads();

    // ---- flush hx (bbS) coalesced: 16 consecutive floats per token
    for (int idx = tid; idx < TM * 4; idx += 512) {
        int t = idx >> 2, g = (idx & 3) * 4;
        const float* hp = bbS + t * SST + g;
        *(float4*)(rec + (bt0 + t) * REC + 16 + g) =
            make_float4(hp[0], hp[1], hp[2], hp[3]);
    }
}

// ---------------------------------------------------------------------------
// Phase 2: sequence-parallel Kalman scan. Block = (b, chunk c). Chunk owns
// t in [c*CL, (c+1)*CL); warm-started WU steps early from generic init.
// ---------------------------------------------------------------------------
__global__ __launch_bounds__(64) void scan_kernel(
    const float* __restrict__ rec, const float* __restrict__ p0,
    float* __restrict__ out_ym, float* __restrict__ out_var,
    float* __restrict__ llsum)
{
    const int blk = blockIdx.x;
    const int b   = blk / NC;
    const int c   = blk - b * NC;
    const int t0  = c * CL;                 // first owned step
    const int ts  = (c == 0) ? 0 : (t0 - WU);
    const int nst = t0 + CL - ts;           // total steps this block runs

    const int l  = threadIdx.x;
    const int d8 = l >> 3, c8 = l & 7;        // (row d, col-group) for CP/S/GJ
    const int i4 = l >> 2, j4 = (l & 3) * 4;  // (row i, col-block) for P stage

    __shared__ __align__(16) float Ps[2][REC];     // double-buffered record
    __shared__ __align__(16) float Pm[16 * 20];    // P, row stride 20 (padded)
    __shared__ __align__(16) float CPm[8 * 20];    // CP rows [d][m], stride 20
    __shared__ __align__(16) float CPT[16 * 12];   // CP^T rows [m][d], stride 12
    __shared__ __align__(16) float XT[16 * 12];    // X^T rows  [m][d], stride 12
    __shared__ __align__(16) float hS[NS];
    __shared__ __align__(16) float hpredS[NS];
    __shared__ __align__(16) float v8[DYV];

    // init: h = 0, P = diag(|p0|)  (exact for c==0; warmup-forgotten otherwise)
    {
        float pv = fabsf(p0[i4]);
        float4 t4;
        t4.x = (j4 + 0 == i4) ? pv : 0.f;  t4.y = (j4 + 1 == i4) ? pv : 0.f;
        t4.z = (j4 + 2 == i4) ? pv : 0.f;  t4.w = (j4 + 3 == i4) ? pv : 0.f;
        *(float4*)(Pm + i4 * 20 + j4) = t4;
        if (l < NS) hS[l] = 0.f;
    }
    const float4* rec4 = (const float4*)(rec + ((size_t)b * TSEQ + ts) * REC);
    float4 pf;
    if (l < 48) {
        ((float4*)Ps[0])[l] = rec4[l];     // record for first step
        pf = rec4[48 + l];                 // next record in flight
    }
    FENCE();

    float accll = 0.f;
    for (int k = 0; k < nst; ++k) {
        const int  t   = ts + k;
        const bool own = (t >= t0);
        const float* R_ = Ps[k & 1];
        float*       W_ = Ps[(k & 1) ^ 1];
        const int m0 = 2 * c8, m1 = m0 + 1;

        // ---- hpred = ez*h + hx (lanes 0..15) -> LDS; yp uses C.hpred
        if (l < NS) hpredS[l] = R_[l] * hS[l] + R_[16 + l];
        FENCE();

        // ---- CP stage + folded y_pred.
        float cz[16];
        float4 c0, c1, c2, c3;
        {
            const float4* C4 = (const float4*)(R_ + 48 + 16 * d8);
            const float4* E4 = (const float4*)R_;
            c0 = C4[0]; c1 = C4[1]; c2 = C4[2]; c3 = C4[3];
            float4 e0 = E4[0], e1 = E4[1], e2 = E4[2], e3 = E4[3];
            cz[0]=c0.x*e0.x; cz[1]=c0.y*e0.y; cz[2]=c0.z*e0.z; cz[3]=c0.w*e0.w;
            cz[4]=c1.x*e1.x; cz[5]=c1.y*e1.y; cz[6]=c1.z*e1.z; cz[7]=c1.w*e1.w;
            cz[8]=c2.x*e2.x; cz[9]=c2.y*e2.y; cz[10]=c2.z*e2.z; cz[11]=c2.w*e2.w;
            cz[12]=c3.x*e3.x; cz[13]=c3.y*e3.y; cz[14]=c3.z*e3.z; cz[15]=c3.w*e3.w;
        }
        float e_save = 0.f;
        {
            const float4* HP = (const float4*)hpredS;
            float yp = dot4_(c0, HP[0]) + dot4_(c1, HP[1])
                     + dot4_(c2, HP[2]) + dot4_(c3, HP[3]);
            if (c8 == 0) {
                e_save = R_[184 + d8] - yp;
                if (own) out_ym[((size_t)b * TSEQ + t) * 8 + d8] = yp;
            }
        }
        {
            float ezm0 = R_[m0],        ezm1 = R_[m1];
            float qm0  = R_[32 + m0],   qm1  = R_[32 + m1];
            float Cd0  = R_[48 + 16 * d8 + m0], Cd1 = R_[48 + 16 * d8 + m1];
            float cp0 = ezm0 * dot16a(cz, Pm + m0 * 20) + Cd0 * qm0;
            float cp1 = ezm1 * dot16a(cz, Pm + m1 * 20) + Cd1 * qm1;
            CPm[d8 * 20 + m0] = cp0;  CPm[d8 * 20 + m1] = cp1;
            CPT[m0 * 12 + d8] = cp0;  CPT[m1 * 12 + d8] = cp1;
        }
        FENCE();

        // ---- S stage: augmented row [S(8) | CP(16) | e] distributed 4/lane
        float a0, a1, a2, a3;
        {
            const float4* CPr = (const float4*)(CPm + d8 * 20);
            const float4* Ce  = (const float4*)(R_ + 48 + 16 * c8);
            a0 = dot4_(CPr[0], Ce[0]) + dot4_(CPr[1], Ce[1])
               + dot4_(CPr[2], Ce[2]) + dot4_(CPr[3], Ce[3]);
            a1 = CPm[d8 * 20 + c8];
            a2 = CPm[d8 * 20 + c8 + 8];
            a3 = e_save;
            if (d8 == c8) {
                a0 += R_[176 + d8];
                if (own) out_var[((size_t)b * TSEQ + t) * 8 + d8] = a0;
            }
        }
        // stage next record + prefetch (independent of the chain)
        if (l < 48) {
            ((float4*)W_)[l] = pf;
            if (k + 2 < nst) pf = rec4[(size_t)(k + 2) * 48 + l];
        }
        FENCE();

        // ---- Gauss-Jordan on [S | CP | e]: ends as [I | X | v], det = prod piv
        // piv and b3 are uniform broadcasts from compile-time lanes -> readlane
        float pdet = 1.f;
        #pragma unroll
        for (int kk = 0; kk < 8; ++kk) {
            float piv = rdlane(a0, kk * 9);
            float b3  = rdlane(a3, kk * 8);
            float f_  = __shfl(a0, (d8 << 3) | kk, 64);
            float b0  = __shfl(a0, (kk << 3) | c8, 64);
            float b1  = __shfl(a1, (kk << 3) | c8, 64);
            float b2  = __shfl(a2, (kk << 3) | c8, 64);
            pdet *= piv;
            float ip = __builtin_amdgcn_rcpf(piv);
            ip = ip * (2.f - piv * ip);            // Newton: full fp32 rcp
            float fr = f_ * ip;
            if (d8 == kk) { a0 *= ip; a1 *= ip; a2 *= ip; a3 *= ip; }
            else          { a0 -= fr * b0; a1 -= fr * b1; a2 -= fr * b2; a3 -= fr * b3; }
        }

        // ---- publish X^T, v
        XT[c8 * 12 + d8]       = a1;
        XT[(c8 + 8) * 12 + d8] = a2;
        if (c8 == 0) v8[d8] = a3;
        FENCE();

        // log-likelihood (lanes c8==0 hold v[d8]; reduce over d8)
        {
            float qp = e_save * a3;
            qp += __shfl_xor(qp, 8, 64);
            qp += __shfl_xor(qp, 16, 64);
            qp += __shfl_xor(qp, 32, 64);
            if (l == 0 && own) accll += -0.5f * (logf(pdet) + qp + 8.f * LOG2PI_F);
        }
        // h_new (lanes 0..15): h = hpred + CP^T v
        if (l < NS) {
            const float4* ct = (const float4*)(CPT + l * 12);
            const float4* vv = (const float4*)v8;
            hS[l] = hpredS[l] + dot4_(ct[0], vv[0]) + dot4_(ct[1], vv[1]);
        }

        // ---- P_new = Ppred - CP^T X (symmetric in exact arithmetic)
        {
            const float4* ct = (const float4*)(CPT + i4 * 12);
            float4 ca = ct[0], cb = ct[1];
            float  ezi = R_[i4];
            float4 ezj = *(const float4*)(R_ + j4);
            float  qi  = R_[32 + i4];
            float4 po  = *(const float4*)(Pm + i4 * 20 + j4);
            float pol[4]  = {po.x, po.y, po.z, po.w};
            float ezjl[4] = {ezj.x, ezj.y, ezj.z, ezj.w};
            float pn[4];
            #pragma unroll
            for (int m = 0; m < 4; ++m) {
                int j = j4 + m;
                const float4* xt = (const float4*)(XT + j * 12);
                float dt = dot4_(ca, xt[0]) + dot4_(cb, xt[1]);
                float pp = ezi * ezjl[m] * pol[m] + ((j == i4) ? qi : 0.f);
                pn[m] = pp - dt;
            }
            *(float4*)(Pm + i4 * 20 + j4) = make_float4(pn[0], pn[1], pn[2], pn[3]);
        }
        FENCE();
    }
    if (l == 0) llsum[blk] = accll;
}

// ---------------------------------------------------------------------------
// Phase 3: scalars (sum NB*NC partial ll sums)
// ---------------------------------------------------------------------------
__global__ void finalize_kernel(const float* __restrict__ llsum,
                                float* __restrict__ out)
{
    if (blockIdx.x != 0) return;
    int l = threadIdx.x;
    float s = 0.f;
    for (int i = l; i < NB * NC; i += 64) s += llsum[i];
    #pragma unroll
    for (int off = 1; off < 64; off <<= 1) s += __shfl_xor(s, off, 64);
    if (l == 0) {
        out[(size_t)2 * BT * DYV]     = -s / (float)NB;        // nll
        out[(size_t)2 * BT * DYV + 1] =  s / (float)BT;        // avg_ll_per_step
    }
}

extern "C" void kernel_launch(void* const* d_in, const int* in_sizes, int n_in,
                              void* d_out, int out_size, void* d_ws, size_t ws_size,
                              hipStream_t stream) {
    const float* x     = (const float*)d_in[0];
    const float* y     = (const float*)d_in[1];
    const float* a_raw = (const float*)d_in[2];
    const float* Wg    = (const float*)d_in[3];
    const float* bg    = (const float*)d_in[4];
    const float* WBm   = (const float*)d_in[5];
    const float* bB    = (const float*)d_in[6];
    const float* WC    = (const float*)d_in[7];
    const float* bC    = (const float*)d_in[8];
    const float* Wsg   = (const float*)d_in[9];
    const float* bsg   = (const float*)d_in[10];
    const float* WR    = (const float*)d_in[11];
    const float* bR    = (const float*)d_in[12];
    const float* p0    = (const float*)d_in[13];

    float* rec   = (float*)d_ws;                        // 65536*192*4 = 50.3 MB
    float* llsum = rec + (size_t)BT * REC;              // + NB*NC floats
    _Float16* WBh = (_Float16*)(llsum + NB * NC);       // 2048*128 fp16 swizzled
    _Float16* WHh = WBh + 2048 * 128;                   // 176*128 fp16 swizzled
    float* out   = (float*)d_out;

    prep_kernel<<<(2048 * 128 + 11 * 2048 + 255) / 256, 256, 0, stream>>>(
        WBm, Wg, Wsg, WR, WC, bB, WBh, WHh);
    proj_kernel<<<BT / TM, 512, 0, stream>>>(x, y, a_raw, bg, bsg, bR, bC,
                                             WBh, WHh, rec);
    scan_kernel<<<NB * NC, 64, 0, stream>>>(rec, p0, out, out + (size_t)BT * DYV,
                                            llsum);
    finalize_kernel<<<1, 64, 0, stream>>>(llsum, out);
}

// Round 17
// 286.536 us; speedup vs baseline: 1.2108x; 1.0094x over previous
//
#include <hip/hip_runtime.h>
#include <math.h>

// ---------------------------------------------------------------------------
// ProbMambaHead: time-varying SSM + per-step Kalman filter.
// Phase 0 (prep_kernel): cast W_B + head weights to fp16, PRE-SWIZZLED into
//   MFMA fragment lane order.
// Phase 1 (proj_kernel): MFMA projections, TM=256 tokens/block, 512 thr
//   (8 waves, 1 block/CU): all waves sweep W_i in phase -> W_i fetched to L1
//   once per CU per i. xv contraction fragments hoisted AND pre-converted to
//   fp32 (removes 1024 v_cvt/wave from the i-loop). hx flushed coalesced.
// Phase 2 (scan_kernel): sequence-parallel Kalman scan, 64 chunks x 32 owned
//   steps, 9-step warm-up. CL=32 = measured latency/DS-throughput balance.
//   llsum[blk] per block (no same-address atomics) + tiny finalize kernel.
// Phase 3 (finalize_kernel): nll / avg_ll scalars.
// ---------------------------------------------------------------------------

#define FENCE() asm volatile("" ::: "memory")   // compiler-only fence; DS ops
// within one wave execute in order, so wave-synchronous LDS needs no barrier.

constexpr int NB   = 32;
constexpr int TSEQ = 2048;
constexpr int BT   = NB * TSEQ;   // 65536
constexpr int DF   = 128;
constexpr int NS   = 16;          // state dim n
constexpr int DYV  = 8;           // obs dim dy
constexpr int REC  = 192;         // floats per (b,t) record (48 float4)
constexpr int TM   = 256;         // tokens per proj block
constexpr int SST  = 17;          // sigS/bbS row stride (pad 16 -> 17)

constexpr int CL   = 32;          // owned steps per scan chunk (measured opt)
constexpr int WU   = 9;           // warmup steps
constexpr int NC   = TSEQ / CL;   // 64 chunks per batch

#define LOG2PI_F 1.8378770664093453f

typedef __attribute__((ext_vector_type(8))) _Float16 f16x8;
typedef __attribute__((ext_vector_type(4))) _Float16 f16x4;
typedef __attribute__((ext_vector_type(4))) float    f32x4;

__device__ __forceinline__ float sp_(float v) {          // jax.nn.softplus
    return v > 0.f ? v + log1pf(expf(-v)) : log1pf(expf(v));
}
__device__ __forceinline__ float dot4_(float4 a, float4 b) {
    return a.x*b.x + a.y*b.y + a.z*b.z + a.w*b.w;
}
__device__ __forceinline__ float dot16a(const float cz[16], const float* p) {
    const float4* p4 = (const float4*)p;
    float4 x0 = p4[0], x1 = p4[1], x2 = p4[2], x3 = p4[3];
    return cz[0]*x0.x + cz[1]*x0.y + cz[2]*x0.z + cz[3]*x0.w
         + cz[4]*x1.x + cz[5]*x1.y + cz[6]*x1.z + cz[7]*x1.w
         + cz[8]*x2.x + cz[9]*x2.y + cz[10]*x2.z + cz[11]*x2.w
         + cz[12]*x3.x + cz[13]*x3.y + cz[14]*x3.z + cz[15]*x3.w;
}
// uniform broadcast from a compile-time lane: scalar pipe, not DS
__device__ __forceinline__ float rdlane(float v, int lane) {
    return __int_as_float(__builtin_amdgcn_readlane(__float_as_int(v), lane));
}

// ---------------------------------------------------------------------------
// Phase 0: weight cast to fp16, swizzled into MFMA fragment lane order.
// WBh (A-fragment order): flat = i*16384 + p*512 + l*8 + j, p = ft*4+ch;
//   source = M_i[ft*16 + (l&15)][ch*32 + (l>>4)*8 + j].
// WHh (B-fragment order): flat = ((nt*4+ch)*64 + l)*8 + j;
//   head h = nt*16 + (l&15); k = ch*32 + (l>>4)*8 + j.
//   h<128: C row h | 128..143: sig | 144..151: R | 152: gate | 153..168: bB
//   | 169..175: zero.
// ---------------------------------------------------------------------------
__global__ __launch_bounds__(256) void prep_kernel(
    const float* __restrict__ WBm, const float* __restrict__ Wg,
    const float* __restrict__ Wsg, const float* __restrict__ WR,
    const float* __restrict__ WC,  const float* __restrict__ bB,
    _Float16* __restrict__ WBh, _Float16* __restrict__ WHh)
{
    int idx = blockIdx.x * 256 + threadIdx.x;
    if (idx < 2048 * 128) {
        int j = idx & 7, l = (idx >> 3) & 63, p = (idx >> 9) & 31, i = idx >> 14;
        int row = (p >> 2) * 16 + (l & 15);
        int col = (p & 3) * 32 + (l >> 4) * 8 + j;
        WBh[idx] = (_Float16)WBm[((size_t)i * 128 + row) * 128 + col];
        return;
    }
    idx -= 2048 * 128;
    if (idx >= 11 * 2048) return;            // 11 tiles * 4 * 64 * 8 = 22528
    int j = idx & 7, l = (idx >> 3) & 63, ch = (idx >> 9) & 3, nt = idx >> 11;
    int h = nt * 16 + (l & 15);
    int g = ch * 32 + (l >> 4) * 8 + j;
    float v;
    if (h < 128)       v = WC[h * 128 + g];
    else if (h < 144)  v = Wsg[(h - 128) * 128 + g];
    else if (h < 152)  v = WR[(h - 144) * 128 + g];
    else if (h == 152) v = Wg[g];
    else if (h < 169)  v = bB[(h - 153) * 128 + g];
    else               v = 0.f;
    WHh[idx] = (_Float16)v;
}

// ---------------------------------------------------------------------------
// Phase 1: MFMA projections. Block = 512 thr (8 waves), 256 tokens.
// Record layout: [0:16) exp_z | [16:32) hx | [32:48) q | [48:176) C (d*16+j)
//                | [176:184) R | [184:192) y.
// ---------------------------------------------------------------------------
__global__ __launch_bounds__(512) void proj_kernel(
    const float* __restrict__ x, const float* __restrict__ y,
    const float* __restrict__ a_raw,
    const float* __restrict__ bg, const float* __restrict__ bsg,
    const float* __restrict__ bR, const float* __restrict__ bC,
    const _Float16* __restrict__ WBh, const _Float16* __restrict__ WHh,
    float* __restrict__ rec)
{
    __shared__ __align__(16) _Float16 Xs[TM * 136];   // [tok][f] fp16, pad 136
    __shared__ __align__(16) float Dsh[TM];           // Delta
    __shared__ __align__(16) float sigS[TM * SST];    // sigma -> gamma*Delta
    __shared__ __align__(16) float bbS[TM * SST];     // bB.x -> (stage Q) hx

    const int tid = threadIdx.x;
    const long bt0 = (long)blockIdx.x * TM;
    const int l  = tid & 63, w = tid >> 6;            // w in [0,8)
    const int lm = l & 15,  lg = l >> 4;

    // ---- stage X: load fp32 tile -> fp16 LDS; y -> rec
    {
        const float4* x4 = (const float4*)(x + bt0 * DF);
        #pragma unroll
        for (int k = 0; k < 16; ++k) {
            int idx = tid + k * 512;           // 8192 float4 = 256x128
            int tok = idx >> 5, fg = idx & 31;
            float4 v = x4[idx];
            f16x4 hv = { (_Float16)v.x, (_Float16)v.y, (_Float16)v.z, (_Float16)v.w };
            *(f16x4*)(Xs + tok * 136 + fg * 4) = hv;
        }
        float4 yv = ((const float4*)(y + bt0 * DYV))[tid];   // 512 float4
        *(float4*)(rec + (bt0 + (tid >> 1)) * REC + 184 + (tid & 1) * 4) = yv;
    }
    __syncthreads();

    // ---- stage H: head GEMM, wave w owns token-tiles {2w, 2w+1}.
    for (int nt = 0; nt < 11; ++nt) {
        f16x8 wf[4];
        #pragma unroll
        for (int ch = 0; ch < 4; ++ch)
            wf[ch] = *(const f16x8*)(WHh + ((nt * 4 + ch) * 64 + l) * 8);
        #pragma unroll
        for (int tt2 = 0; tt2 < 2; ++tt2) {
            const int tt = 2 * w + tt2;
            f32x4 acc = {0.f, 0.f, 0.f, 0.f};
            #pragma unroll
            for (int ch = 0; ch < 4; ++ch) {
                f16x8 xf = *(const f16x8*)(Xs + (tt * 16 + lm) * 136 + ch * 32 + lg * 8);
                acc = __builtin_amdgcn_mfma_f32_16x16x32_f16(xf, wf[ch], acc, 0, 0, 0);
            }
            const int tokb = tt * 16 + lg * 4;           // + reg
            if (nt < 8) {                                // pure C tiles
                float bias = bC[nt * 16 + lm];
                #pragma unroll
                for (int rg = 0; rg < 4; ++rg)
                    rec[(bt0 + tokb + rg) * REC + 48 + nt * 16 + lm] = acc[rg] + bias;
            } else if (nt == 8) {                        // pure sig tile
                float bias = bsg[lm];
                #pragma unroll
                for (int rg = 0; rg < 4; ++rg)
                    sigS[(tokb + rg) * SST + lm] = sp_(acc[rg] + bias) + 1e-6f + 1e-3f;
            } else if (nt == 9) {                        // R | gate | bB 0..6
                #pragma unroll
                for (int rg = 0; rg < 4; ++rg) {
                    int tok = tokb + rg; float v = acc[rg];
                    if (lm < 8)
                        rec[(bt0 + tok) * REC + 176 + lm] = sp_(v + bR[lm]) + 1e-6f + 1e-4f;
                    else if (lm == 8)
                        Dsh[tok] = fminf(fmaxf(sp_(v + bg[0]) + 1e-6f, 1e-3f), 1.0f);
                    else
                        bbS[tok * SST + (lm - 9)] = v;
                }
            } else {                                     // bB 7..15 | pad
                #pragma unroll
                for (int rg = 0; rg < 4; ++rg)
                    if (lm < 9) bbS[(tokb + rg) * SST + 7 + lm] = acc[rg];
            }
        }
    }
    __syncthreads();

    // ---- stage Z: per (t,i) ez/q; sigS becomes gamma*Delta in place
    for (int p = tid; p < TM * NS; p += 512) {
        int t = p >> 4, i = p & 15;
        float D  = Dsh[t];
        float a  = -(sp_(a_raw[i]) + 1e-6f);
        float z  = fminf(fmaxf(D * a, -20.f), 20.f);
        float ez = expf(z);
        float gam = (fabsf(z) < 1e-4f) ? (1.f + 0.5f * z) : (expm1f(z) / z);
        float z2  = 2.f * z;
        float rho = (fabsf(z2) < 1e-4f) ? (1.f + 0.5f * z2) : (expm1f(z2) / z2);
        float sg  = sigS[t * SST + i];
        long base = (bt0 + t) * REC;
        rec[base + i]      = ez;
        rec[base + 32 + i] = sg * sg * rho * D;
        sigS[t * SST + i] = gam * D;             // now gamma*Delta
    }
    __syncthreads();                             // sigS/bbS ready for epilogue

    // ---- hoist B-fragments and xv contraction values (i-invariant),
    //      xv pre-converted to fp32: no v_cvt inside the i-loop.
    f16x8 b0[4], b1[4];
    float xw0[32], xw1[32];
    #pragma unroll
    for (int ch = 0; ch < 4; ++ch) {
        b0[ch] = *(const f16x8*)(Xs + ((2 * w) * 16 + lm) * 136 + ch * 32 + lg * 8);
        b1[ch] = *(const f16x8*)(Xs + ((2 * w + 1) * 16 + lm) * 136 + ch * 32 + lg * 8);
    }
    #pragma unroll
    for (int ft = 0; ft < 8; ++ft) {
        f16x4 a = *(const f16x4*)(Xs + ((2 * w) * 16 + lm) * 136 + ft * 16 + lg * 4);
        f16x4 b = *(const f16x4*)(Xs + ((2 * w + 1) * 16 + lm) * 136 + ft * 16 + lg * 4);
        #pragma unroll
        for (int k = 0; k < 4; ++k) {
            xw0[ft * 4 + k] = (float)a[k];
            xw1[ft * 4 + k] = (float)b[k];
        }
    }

    // ---- stage Q: quadratic form. All 8 waves sweep i in phase: W_i (32KB)
    // is fetched into L1 once per CU per i. hx -> bbS in place (LDS).
    for (int i = 0; i < 16; ++i) {
        const _Float16* Wi = WBh + (size_t)i * 16384;
        f32x4 acc[2][8];
        #pragma unroll
        for (int tt = 0; tt < 2; ++tt)
            #pragma unroll
            for (int ft = 0; ft < 8; ++ft) acc[tt][ft] = (f32x4){0.f, 0.f, 0.f, 0.f};
        #pragma unroll
        for (int ch = 0; ch < 4; ++ch) {
            f16x8 af[8];
            #pragma unroll
            for (int ft = 0; ft < 8; ++ft)
                af[ft] = *(const f16x8*)(Wi + (ft * 4 + ch) * 512 + l * 8);
            #pragma unroll
            for (int ft = 0; ft < 8; ++ft) {
                acc[0][ft] = __builtin_amdgcn_mfma_f32_16x16x32_f16(af[ft], b0[ch], acc[0][ft], 0, 0, 0);
                acc[1][ft] = __builtin_amdgcn_mfma_f32_16x16x32_f16(af[ft], b1[ch], acc[1][ft], 0, 0, 0);
            }
        }
        // in-register contraction over f (fp32 xw hoisted), then 2 shfl hops
        #pragma unroll
        for (int tt = 0; tt < 2; ++tt) {
            const float* xw = tt ? xw1 : xw0;
            float part = 0.f;
            #pragma unroll
            for (int ft = 0; ft < 8; ++ft) {
                part += acc[tt][ft][0] * xw[ft * 4 + 0] + acc[tt][ft][1] * xw[ft * 4 + 1]
                      + acc[tt][ft][2] * xw[ft * 4 + 2] + acc[tt][ft][3] * xw[ft * 4 + 3];
            }
            part += __shfl_xor(part, 16, 64);
            part += __shfl_xor(part, 32, 64);
            if (l < 16) {
                int t = (2 * w + tt) * 16 + l;
                bbS[t * SST + i] = sigS[t * SST + i] * (part + bbS[t * SST + i]);
            }
        }
    }
    __syncthreads();

    // ---- flush hx (bbS) coalesced: 16 consecutive floats per token
    for (int idx = tid; idx < TM * 4; idx += 512) {
        int t = idx >> 2, g = (idx & 3) * 4;
        const float* hp = bbS + t * SST + g;
        *(float4*)(rec + (bt0 + t) * REC + 16 + g) =
            make_float4(hp[0], hp[1], hp[2], hp[3]);
    }
}

// ---------------------------------------------------------------------------
// Phase 2: sequence-parallel Kalman scan. Block = (b, chunk c). Chunk owns
// t in [c*CL, (c+1)*CL); warm-started WU steps early from generic init.
// ---------------------------------------------------------------------------
__global__ __launch_bounds__(64) void scan_kernel(
    const float* __restrict__ rec, const float* __restrict__ p0,
    float* __restrict__ out_ym, float* __restrict__ out_var,
    float* __restrict__ llsum)
{
    const int blk = blockIdx.x;
    const int b   = blk / NC;
    const int c   = blk - b * NC;
    const int t0  = c * CL;                 // first owned step
    const int ts  = (c == 0) ? 0 : (t0 - WU);
    const int nst = t0 + CL - ts;           // total steps this block runs

    const int l  = threadIdx.x;
    const int d8 = l >> 3, c8 = l & 7;        // (row d, col-group) for CP/S/GJ
    const int i4 = l >> 2, j4 = (l & 3) * 4;  // (row i, col-block) for P stage

    __shared__ __align__(16) float Ps[2][REC];     // double-buffered record
    __shared__ __align__(16) float Pm[16 * 20];    // P, row stride 20 (padded)
    __shared__ __align__(16) float CPm[8 * 20];    // CP rows [d][m], stride 20
    __shared__ __align__(16) float CPT[16 * 12];   // CP^T rows [m][d], stride 12
    __shared__ __align__(16) float XT[16 * 12];    // X^T rows  [m][d], stride 12
    __shared__ __align__(16) float hS[NS];
    __shared__ __align__(16) float hpredS[NS];
    __shared__ __align__(16) float v8[DYV];

    // init: h = 0, P = diag(|p0|)  (exact for c==0; warmup-forgotten otherwise)
    {
        float pv = fabsf(p0[i4]);
        float4 t4;
        t4.x = (j4 + 0 == i4) ? pv : 0.f;  t4.y = (j4 + 1 == i4) ? pv : 0.f;
        t4.z = (j4 + 2 == i4) ? pv : 0.f;  t4.w = (j4 + 3 == i4) ? pv : 0.f;
        *(float4*)(Pm + i4 * 20 + j4) = t4;
        if (l < NS) hS[l] = 0.f;
    }
    const float4* rec4 = (const float4*)(rec + ((size_t)b * TSEQ + ts) * REC);
    float4 pf;
    if (l < 48) {
        ((float4*)Ps[0])[l] = rec4[l];     // record for first step
        pf = rec4[48 + l];                 // next record in flight
    }
    FENCE();

    float accll = 0.f;
    for (int k = 0; k < nst; ++k) {
        const int  t   = ts + k;
        const bool own = (t >= t0);
        const float* R_ = Ps[k & 1];
        float*       W_ = Ps[(k & 1) ^ 1];
        const int m0 = 2 * c8, m1 = m0 + 1;

        // ---- hpred = ez*h + hx (lanes 0..15) -> LDS; yp uses C.hpred
        if (l < NS) hpredS[l] = R_[l] * hS[l] + R_[16 + l];
        FENCE();

        // ---- CP stage + folded y_pred.
        float cz[16];
        float4 c0, c1, c2, c3;
        {
            const float4* C4 = (const float4*)(R_ + 48 + 16 * d8);
            const float4* E4 = (const float4*)R_;
            c0 = C4[0]; c1 = C4[1]; c2 = C4[2]; c3 = C4[3];
            float4 e0 = E4[0], e1 = E4[1], e2 = E4[2], e3 = E4[3];
            cz[0]=c0.x*e0.x; cz[1]=c0.y*e0.y; cz[2]=c0.z*e0.z; cz[3]=c0.w*e0.w;
            cz[4]=c1.x*e1.x; cz[5]=c1.y*e1.y; cz[6]=c1.z*e1.z; cz[7]=c1.w*e1.w;
            cz[8]=c2.x*e2.x; cz[9]=c2.y*e2.y; cz[10]=c2.z*e2.z; cz[11]=c2.w*e2.w;
            cz[12]=c3.x*e3.x; cz[13]=c3.y*e3.y; cz[14]=c3.z*e3.z; cz[15]=c3.w*e3.w;
        }
        float e_save = 0.f;
        {
            const float4* HP = (const float4*)hpredS;
            float yp = dot4_(c0, HP[0]) + dot4_(c1, HP[1])
                     + dot4_(c2, HP[2]) + dot4_(c3, HP[3]);
            if (c8 == 0) {
                e_save = R_[184 + d8] - yp;
                if (own) out_ym[((size_t)b * TSEQ + t) * 8 + d8] = yp;
            }
        }
        {
            float ezm0 = R_[m0],        ezm1 = R_[m1];
            float qm0  = R_[32 + m0],   qm1  = R_[32 + m1];
            float Cd0  = R_[48 + 16 * d8 + m0], Cd1 = R_[48 + 16 * d8 + m1];
            float cp0 = ezm0 * dot16a(cz, Pm + m0 * 20) + Cd0 * qm0;
            float cp1 = ezm1 * dot16a(cz, Pm + m1 * 20) + Cd1 * qm1;
            *(float2*)(CPm + d8 * 20 + m0) = make_float2(cp0, cp1);  // packed b64
            CPT[m0 * 12 + d8] = cp0;  CPT[m1 * 12 + d8] = cp1;
        }
        FENCE();

        // ---- S stage: augmented row [S(8) | CP(16) | e] distributed 4/lane
        float a0, a1, a2, a3;
        {
            const float4* CPr = (const float4*)(CPm + d8 * 20);
            const float4* Ce  = (const float4*)(R_ + 48 + 16 * c8);
            a0 = dot4_(CPr[0], Ce[0]) + dot4_(CPr[1], Ce[1])
               + dot4_(CPr[2], Ce[2]) + dot4_(CPr[3], Ce[3]);
            a1 = CPm[d8 * 20 + c8];
            a2 = CPm[d8 * 20 + c8 + 8];
            a3 = e_save;
            if (d8 == c8) {
                a0 += R_[176 + d8];
                if (own) out_var[((size_t)b * TSEQ + t) * 8 + d8] = a0;
            }
        }
        // stage next record + prefetch (independent of the chain)
        if (l < 48) {
            ((float4*)W_)[l] = pf;
            if (k + 2 < nst) pf = rec4[(size_t)(k + 2) * 48 + l];
        }
        FENCE();

        // ---- Gauss-Jordan on [S | CP | e]: ends as [I | X | v], det = prod piv
        // piv and b3 are uniform broadcasts from compile-time lanes -> readlane
        float pdet = 1.f;
        #pragma unroll
        for (int kk = 0; kk < 8; ++kk) {
            float piv = rdlane(a0, kk * 9);
            float b3  = rdlane(a3, kk * 8);
            float f_  = __shfl(a0, (d8 << 3) | kk, 64);
            float b0  = __shfl(a0, (kk << 3) | c8, 64);
            float b1  = __shfl(a1, (kk << 3) | c8, 64);
            float b2  = __shfl(a2, (kk << 3) | c8, 64);
            pdet *= piv;
            float ip = __builtin_amdgcn_rcpf(piv);
            ip = ip * (2.f - piv * ip);            // Newton: full fp32 rcp
            float fr = f_ * ip;
            if (d8 == kk) { a0 *= ip; a1 *= ip; a2 *= ip; a3 *= ip; }
            else          { a0 -= fr * b0; a1 -= fr * b1; a2 -= fr * b2; a3 -= fr * b3; }
        }

        // ---- publish X^T, v
        XT[c8 * 12 + d8]       = a1;
        XT[(c8 + 8) * 12 + d8] = a2;
        if (c8 == 0) v8[d8] = a3;
        FENCE();

        // log-likelihood (lanes c8==0 hold v[d8]; reduce over d8)
        {
            float qp = e_save * a3;
            qp += __shfl_xor(qp, 8, 64);
            qp += __shfl_xor(qp, 16, 64);
            qp += __shfl_xor(qp, 32, 64);
            if (l == 0 && own) accll += -0.5f * (logf(pdet) + qp + 8.f * LOG2PI_F);
        }
        // h_new (lanes 0..15): h = hpred + CP^T v
        if (l < NS) {
            const float4* ct = (const float4*)(CPT + l * 12);
            const float4* vv = (const float4*)v8;
            hS[l] = hpredS[l] + dot4_(ct[0], vv[0]) + dot4_(ct[1], vv[1]);
        }

        // ---- P_new = Ppred - CP^T X (symmetric in exact arithmetic)
        {
            const float4* ct = (const float4*)(CPT + i4 * 12);
            float4 ca = ct[0], cb = ct[1];
            float  ezi = R_[i4];
            float4 ezj = *(const float4*)(R_ + j4);
            float  qi  = R_[32 + i4];
            float4 po  = *(const float4*)(Pm + i4 * 20 + j4);
            float pol[4]  = {po.x, po.y, po.z, po.w};
            float ezjl[4] = {ezj.x, ezj.y, ezj.z, ezj.w};
            float pn[4];
            #pragma unroll
            for (int m = 0; m < 4; ++m) {
                int j = j4 + m;
                const float4* xt = (const float4*)(XT + j * 12);
                float dt = dot4_(ca, xt[0]) + dot4_(cb, xt[1]);
                float pp = ezi * ezjl[m] * pol[m] + ((j == i4) ? qi : 0.f);
                pn[m] = pp - dt;
            }
            *(float4*)(Pm + i4 * 20 + j4) = make_float4(pn[0], pn[1], pn[2], pn[3]);
        }
        FENCE();
    }
    if (l == 0) llsum[blk] = accll;
}

// ---------------------------------------------------------------------------
// Phase 3: scalars (sum NB*NC partial ll sums)
// ---------------------------------------------------------------------------
__global__ void finalize_kernel(const float* __restrict__ llsum,
                                float* __restrict__ out)
{
    if (blockIdx.x != 0) return;
    int l = threadIdx.x;
    float s = 0.f;
    for (int i = l; i < NB * NC; i += 64) s += llsum[i];
    #pragma unroll
    for (int off = 1; off < 64; off <<= 1) s += __shfl_xor(s, off, 64);
    if (l == 0) {
        out[(size_t)2 * BT * DYV]     = -s / (float)NB;        // nll
        out[(size_t)2 * BT * DYV + 1] =  s / (float)BT;        // avg_ll_per_step
    }
}

extern "C" void kernel_launch(void* const* d_in, const int* in_sizes, int n_in,
                              void* d_out, int out_size, void* d_ws, size_t ws_size,
                              hipStream_t stream) {
    const float* x     = (const float*)d_in[0];
    const float* y     = (const float*)d_in[1];
    const float* a_raw = (const float*)d_in[2];
    const float* Wg    = (const float*)d_in[3];
    const float* bg    = (const float*)d_in[4];
    const float* WBm   = (const float*)d_in[5];
    const float* bB    = (const float*)d_in[6];
    const float* WC    = (const float*)d_in[7];
    const float* bC    = (const float*)d_in[8];
    const float* Wsg   = (const float*)d_in[9];
    const float* bsg   = (const float*)d_in[10];
    const float* WR    = (const float*)d_in[11];
    const float* bR    = (const float*)d_in[12];
    const float* p0    = (const float*)d_in[13];

    float* rec   = (float*)d_ws;                        // 65536*192*4 = 50.3 MB
    float* llsum = rec + (size_t)BT * REC;              // + NB*NC floats
    _Float16* WBh = (_Float16*)(llsum + NB * NC);       // 2048*128 fp16 swizzled
    _Float16* WHh = WBh + 2048 * 128;                   // 176*128 fp16 swizzled
    float* out   = (float*)d_out;

    prep_kernel<<<(2048 * 128 + 11 * 2048 + 255) / 256, 256, 0, stream>>>(
        WBm, Wg, Wsg, WR, WC, bB, WBh, WHh);
    proj_kernel<<<BT / TM, 512, 0, stream>>>(x, y, a_raw, bg, bsg, bR, bC,
                                             WBh, WHh, rec);
    scan_kernel<<<NB * NC, 64, 0, stream>>>(rec, p0, out, out + (size_t)BT * DYV,
                                            llsum);
    finalize_kernel<<<1, 64, 0, stream>>>(llsum, out);
}